// Round 4
// baseline (556.302 us; speedup 1.0000x reference)
//
#include <hip/hip_runtime.h>

// ---------------- workspace layout (float/int indices into d_ws) ----------
#define WS_A0 0              // commitment sum
#define WS_A1 1              // sum of E_dist over (n,c)
#define WS_A2 2              // sum of neg_ent over (n,c)
#define WS_QBAR 16           // 8192 floats: sum_n q[n,c,k]
#define WS_CBSQ (WS_QBAR + 8192)   // 8192 floats: ||cb[c,k]||^2
#define WS_IDX  (WS_CBSQ + 8192)   // 32768 ints: argmin index per (n,c)

// ---------------- output layout (floats) ----------------------------------
#define OUT_IDX  1048576     // indices (B,C,H,W) as float
#define OUT_Q    1081344     // q (N,C,K)
#define OUT_SCAL 34635776    // commitment, free_energy, confidence, balance, tau

__global__ __launch_bounds__(256) void k_cbsq(const float* __restrict__ cb,
                                              float* __restrict__ ws_f) {
  int i = blockIdx.x * 256 + threadIdx.x;   // 0..8191  (= c*1024 + k)
  const float* r = cb + (size_t)i * 32;
  float s = 0.f;
#pragma unroll
  for (int d = 0; d < 32; ++d) s = fmaf(r[d], r[d], s);
  ws_f[WS_CBSQ + i] = s;
}

__device__ __forceinline__ float wsum64(float v) {
#pragma unroll
  for (int m = 32; m >= 1; m >>= 1) v += __shfl_xor(v, m, 64);
  return v;
}

__device__ __forceinline__ float uread(float v) {
  // wave-uniform value -> SGPR (exact; all lanes hold the same bits)
  return __int_as_float(__builtin_amdgcn_readfirstlane(__float_as_int(v)));
}

// main: 256 blocks (8 c x 32 n-blocks), 1024 threads (16 waves), 152.5KB LDS.
// R3: two-pass K-sweep fits 128 VGPR (no scratch). R4: NB=2 n-batching.
// R5: 1024-thr blocks + z/cbsq staged to LDS -> 4 waves/EU.
// R6: R5's waves_per_eu(4,4) made the allocator budget 64 VGPRs (observed
// pattern: VGPR = 512/(2*max_waves)) -> forced spill of the ~115-reg working
// set -> 330MB scratch fetch that ate the whole occupancy win. Request
// (2,2): allocator lands at 128 (also the launchability cap for a 16-wave
// block), the R4-proven no-spill budget, while HW residency stays
// 16 waves/CU = 4 waves/SIMD (resource-determined, not attribute-limited).
#define ZLD 33               // z_lds leading dim (+1 pad: write stride 33)
__global__ __launch_bounds__(1024)
__attribute__((amdgpu_waves_per_eu(2, 2)))
void k_main(
    const float* __restrict__ z, const float* __restrict__ cb,
    float* __restrict__ out, float* __restrict__ ws_f, int* __restrict__ ws_i) {
  extern __shared__ float smem[];
  float* cb_lds   = smem;              // 32768 floats, xor-swizzled quads
  float* qsum     = smem + 32768;      // 1024 floats: per-block sum_n q
  float* cbsq_lds = smem + 33792;      // 1024 floats: ||cb[c,k]||^2
  float* z_lds    = smem + 34816;      // 128*33 floats: z[nl, d] (padded)

  const int c    = blockIdx.x >> 5;
  const int nblk = blockIdx.x & 31;
  const int tid  = threadIdx.x;
  const int lane = tid & 63;
  const int wave = tid >> 6;           // 0..15

  const int bb   = (nblk * 128) >> 10;      // batch index, constant per block
  const int hwb  = (nblk * 128) & 1023;     // hw base, constant per block

  // ---- stage full channel codebook into LDS, quad-xor swizzle -------------
  const float4* cb4 = (const float4*)(cb + (size_t)c * 32768);
  float4* lds4 = (float4*)cb_lds;
#pragma unroll
  for (int i = 0; i < 8; ++i) {
    int idx = i * 1024 + tid;           // float4 index 0..8191
    int k = idx >> 3, q = idx & 7;
    lds4[(k << 3) + (q ^ (k & 7))] = cb4[idx];
  }
  qsum[tid] = 0.f;
  cbsq_lds[tid] = ws_f[WS_CBSQ + c * 1024 + tid];
  // z slice: 128 n x 32 d, coalesced global reads, padded LDS writes
  {
    const float* zbase = z + (((size_t)bb * 256 + c * 32) << 10) + hwb;
#pragma unroll
    for (int i = 0; i < 4; ++i) {
      int idx = i * 1024 + tid;         // 0..4095
      int d = idx >> 7, j = idx & 127;
      z_lds[j * ZLD + d] = zbase[(size_t)d * 1024 + j];
    }
  }
  __syncthreads();

  float* out_q   = out + OUT_Q;
  float* out_idx = out + OUT_IDX;

  float accA0 = 0.f, accA1 = 0.f, accA2 = 0.f;
  const int kl7 = lane & 7;

#pragma unroll 1
  for (int pp = 0; pp < 4; ++pp) {      // each wave: 4 pairs of n
    const int nl0 = wave * 8 + pp * 2;  // local n in [0,128)
    const int nl1 = nl0 + 1;
    const int n0 = nblk * 128 + nl0;
    const int n1 = n0 + 1;

    // wave-uniform z (LDS broadcast) -> force into SGPRs
    float zv0[32], zv1[32];
#pragma unroll
    for (int d = 0; d < 32; ++d) {
      zv0[d] = uread(z_lds[nl0 * ZLD + d]);
      zv1[d] = uread(z_lds[nl1 * ZLD + d]);
    }
    float zs0 = 0.f, zs1 = 0.f;
#pragma unroll
    for (int d = 0; d < 32; ++d) {
      zs0 = fmaf(zv0[d], zv0[d], zs0);
      zs1 = fmaf(zv1[d], zv1[d], zs1);
    }

    // ---- pass 1: streaming dot for both n -> e, S, es, argmax -------------
    float e0[16], e1[16];
    float S0 = 0.f, S1 = 0.f, es0 = 0.f, es1 = 0.f;
    float sm0 = -INFINITY, sm1 = -INFINITY;
    int km0 = 0, km1 = 0;

#pragma unroll 2
    for (int jj = 0; jj < 16; ++jj) {   // k = jj*64 + lane, covers K=1024
      const int k = jj * 64 + lane;
      float cq = cbsq_lds[k];
      float a0 = 0.f, a1 = 0.f, a2 = 0.f, a3 = 0.f;
      float g0 = 0.f, g1 = 0.f, g2 = 0.f, g3 = 0.f;
#pragma unroll
      for (int q = 0; q < 8; ++q) {
        float4 r4 = lds4[(k << 3) + (q ^ kl7)];
        a0 = fmaf(r4.x, zv0[q * 4 + 0], a0);
        a1 = fmaf(r4.y, zv0[q * 4 + 1], a1);
        a2 = fmaf(r4.z, zv0[q * 4 + 2], a2);
        a3 = fmaf(r4.w, zv0[q * 4 + 3], a3);
        g0 = fmaf(r4.x, zv1[q * 4 + 0], g0);
        g1 = fmaf(r4.y, zv1[q * 4 + 1], g1);
        g2 = fmaf(r4.z, zv1[q * 4 + 2], g2);
        g3 = fmaf(r4.w, zv1[q * 4 + 3], g3);
      }
      float s0 = (a0 + a1) + (a2 + a3) - 0.5f * cq;  // logits + const(n)
      float s1 = (g0 + g1) + (g2 + g3) - 0.5f * cq;
      float ev0 = __expf(s0), ev1 = __expf(s1);
      e0[jj] = ev0; e1[jj] = ev1;
      S0 += ev0;  S1 += ev1;
      es0 = fmaf(ev0, s0, es0);
      es1 = fmaf(ev1, s1, es1);
      if (s0 > sm0) { sm0 = s0; km0 = k; }
      if (s1 > sm1) { sm1 = s1; km1 = k; }
    }

    float St0 = wsum64(S0), St1 = wsum64(S1);
    float rS0 = 1.f / St0, rS1 = 1.f / St1;
    float est0 = wsum64(es0), est1 = wsum64(es1);

    accA1 += (zs0 - 2.f * est0 * rS0) + (zs1 - 2.f * est1 * rS1);
    accA2 += (est0 * rS0 - __logf(St0)) + (est1 * rS1 - __logf(St1));

    // ---- argmax(s) == argmin(dist), tie -> lower k; retire sm/km early ----
#pragma unroll
    for (int m = 32; m >= 1; m >>= 1) {
      float so = __shfl_xor(sm0, m, 64); int ko = __shfl_xor(km0, m, 64);
      if (so > sm0 || (so == sm0 && ko < km0)) { sm0 = so; km0 = ko; }
      float sp = __shfl_xor(sm1, m, 64); int kp = __shfl_xor(km1, m, 64);
      if (sp > sm1 || (sp == sm1 && kp < km1)) { sm1 = sp; km1 = kp; }
    }
    if (lane == 0) {
      out_idx[(size_t)bb * 8192 + c * 1024 + hwb + nl0] = (float)km0;
      ws_i[WS_IDX + n0 * 8 + c] = km0;
      out_idx[(size_t)bb * 8192 + c * 1024 + hwb + nl1] = (float)km1;
      ws_i[WS_IDX + n1 * 8 + c] = km1;
    }

    // ---- pass 2a: e -> qv (in place), q writes, q_bar LDS atomics ---------
    float* qp0 = out_q + ((size_t)n0 * 8 + c) * 1024;
    float* qp1 = out_q + ((size_t)n1 * 8 + c) * 1024;
#pragma unroll 2
    for (int jj = 0; jj < 16; ++jj) {
      float qv0 = e0[jj] * rS0;
      float qv1 = e1[jj] * rS1;
      e0[jj] = qv0; e1[jj] = qv1;
      __builtin_nontemporal_store(qv0, qp0 + jj * 64 + lane);
      __builtin_nontemporal_store(qv1, qp1 + jj * 64 + lane);
      atomicAdd(&qsum[jj * 64 + lane], qv0 + qv1);
    }

    // ---- pass 2b: re-read LDS rows; zq accumulation for both n ------------
    float zq0[32], zq1[32];
#pragma unroll
    for (int d = 0; d < 32; ++d) { zq0[d] = 0.f; zq1[d] = 0.f; }
#pragma unroll 2
    for (int jj = 0; jj < 16; ++jj) {
      const int k = jj * 64 + lane;
      float qv0 = e0[jj], qv1 = e1[jj];
#pragma unroll
      for (int q = 0; q < 8; ++q) {
        float4 r4 = lds4[(k << 3) + (q ^ kl7)];
        zq0[q * 4 + 0] = fmaf(qv0, r4.x, zq0[q * 4 + 0]);
        zq0[q * 4 + 1] = fmaf(qv0, r4.y, zq0[q * 4 + 1]);
        zq0[q * 4 + 2] = fmaf(qv0, r4.z, zq0[q * 4 + 2]);
        zq0[q * 4 + 3] = fmaf(qv0, r4.w, zq0[q * 4 + 3]);
        zq1[q * 4 + 0] = fmaf(qv1, r4.x, zq1[q * 4 + 0]);
        zq1[q * 4 + 1] = fmaf(qv1, r4.y, zq1[q * 4 + 1]);
        zq1[q * 4 + 2] = fmaf(qv1, r4.z, zq1[q * 4 + 2]);
        zq1[q * 4 + 3] = fmaf(qv1, r4.w, zq1[q * 4 + 3]);
      }
    }

    // ---- split-butterfly reduce zq over 64 lanes; lane -> dd=(lane>>1)&31 --
#pragma unroll
    for (int t = 0; t < 5; ++t) {
      const int half = 16 >> t;
      const int up = (lane >> (5 - t)) & 1;
#pragma unroll
      for (int i = 0; i < half; ++i) {
        float sa0 = up ? zq0[i] : zq0[i + half];
        float ka0 = up ? zq0[i + half] : zq0[i];
        zq0[i] = ka0 + __shfl_xor(sa0, 32 >> t, 64);
        float sa1 = up ? zq1[i] : zq1[i + half];
        float ka1 = up ? zq1[i + half] : zq1[i];
        zq1[i] = ka1 + __shfl_xor(sa1, 32 >> t, 64);
      }
    }
    zq0[0] += __shfl_xor(zq0[0], 1, 64);
    zq1[0] += __shfl_xor(zq1[0], 1, 64);
    const int ddl = (lane >> 1) & 31;
    float zf0 = z_lds[nl0 * ZLD + ddl];
    float zf1 = z_lds[nl1 * ZLD + ddl];
    float d0 = zf0 - zq0[0];             // zq already normalized (qv = e*rS)
    float d1 = zf1 - zq1[0];
    accA0 += 0.5f * wsum64(d0 * d0 + d1 * d1);  // each dd counted twice
  }

  if (lane == 0) {
    atomicAdd(&ws_f[WS_A0], accA0);
    atomicAdd(&ws_f[WS_A1], accA1);
    atomicAdd(&ws_f[WS_A2], accA2);
  }

  // ---- q_bar: block LDS accumulator -> global -----------------------------
  __syncthreads();
  atomicAdd(&ws_f[WS_QBAR + c * 1024 + tid], qsum[tid]);
}

// hard-quantized gather: coalesced writes of cb[c, idx[n,c], dd]
__global__ __launch_bounds__(256) void k_hard(const float* __restrict__ cb,
                                              const int* __restrict__ ws_i,
                                              float* __restrict__ out0) {
  int o = blockIdx.x * 256 + threadIdx.x;    // (b, ch, hw) row-major
  int b  = o >> 18;
  int r  = o & 262143;
  int ch = r >> 10;
  int hw = r & 1023;
  int c = ch >> 5, dd = ch & 31;
  int n = (b << 10) + hw;
  int k = ws_i[WS_IDX + n * 8 + c];
  out0[o] = cb[((size_t)(c << 10) + k) * 32 + dd];
}

__global__ __launch_bounds__(256) void k_final(const float* __restrict__ ws_f,
                                               float* __restrict__ out_s) {
  __shared__ float red[256];
  int tid = threadIdx.x;
  float bal = 0.f;
  for (int i = tid; i < 8192; i += 256) {
    float qb = ws_f[WS_QBAR + i] * (1.0f / 4096.0f);
    bal += qb * __logf(qb * 1024.0f + 1e-8f);
  }
  red[tid] = bal;
  __syncthreads();
  for (int s = 128; s > 0; s >>= 1) {
    if (tid < s) red[tid] += red[tid + s];
    __syncthreads();
  }
  if (tid == 0) {
    float A0 = ws_f[WS_A0], A1 = ws_f[WS_A1], A2 = ws_f[WS_A2];
    out_s[0] = A0 * (1.0f / 1048576.0f);                              // commitment
    out_s[1] = (0.5f * A1 + A2) * (1.0f / 32768.0f) + 6.93147180559945f; // free_energy
    out_s[2] = -A2 * (1.0f / 32768.0f);                               // confidence
    out_s[3] = red[0] * 0.125f;                                       // balance
    out_s[4] = 1.0f;                                                  // tau
  }
}

extern "C" void kernel_launch(void* const* d_in, const int* in_sizes, int n_in,
                              void* d_out, int out_size, void* d_ws, size_t ws_size,
                              hipStream_t stream) {
  (void)in_sizes; (void)n_in; (void)out_size; (void)ws_size;
  const float* z  = (const float*)d_in[0];
  const float* cb = (const float*)d_in[1];
  float* out  = (float*)d_out;
  float* ws_f = (float*)d_ws;
  int*   ws_i = (int*)d_ws;

  // 152.5KB dynamic LDS (> 64KB default): opt in every call (idempotent)
  hipFuncSetAttribute(reinterpret_cast<const void*>(k_main),
                      hipFuncAttributeMaxDynamicSharedMemorySize, 156160);

  hipMemsetAsync(d_ws, 0, (WS_QBAR + 8192) * sizeof(float), stream);
  k_cbsq <<<32,   256, 0,      stream>>>(cb, ws_f);
  k_main <<<256, 1024, 156160, stream>>>(z, cb, out, ws_f, ws_i);
  k_hard <<<4096, 256, 0,      stream>>>(cb, ws_i, out);
  k_final<<<1,    256, 0,      stream>>>(ws_f, out + OUT_SCAL);
}

// Round 5
// 512.691 us; speedup vs baseline: 1.0851x; 1.0851x over previous
//
#include <hip/hip_runtime.h>

// ---------------- workspace layout (float/int indices into d_ws) ----------
#define WS_A0 0              // commitment sum
#define WS_A1 1              // sum of E_dist over (n,c)
#define WS_A2 2              // sum of neg_ent over (n,c)
#define WS_QBAR 16           // 8192 floats: sum_n q[n,c,k]
#define WS_CBSQ (WS_QBAR + 8192)   // 8192 floats: ||cb[c,k]||^2
#define WS_IDX  (WS_CBSQ + 8192)   // 32768 ints: argmin index per (n,c)

// ---------------- output layout (floats) ----------------------------------
#define OUT_IDX  1048576     // indices (B,C,H,W) as float
#define OUT_Q    1081344     // q (N,C,K)
#define OUT_SCAL 34635776    // commitment, free_energy, confidence, balance, tau

__global__ __launch_bounds__(256) void k_cbsq(const float* __restrict__ cb,
                                              float* __restrict__ ws_f) {
  int i = blockIdx.x * 256 + threadIdx.x;   // 0..8191  (= c*1024 + k)
  const float* r = cb + (size_t)i * 32;
  float s = 0.f;
#pragma unroll
  for (int d = 0; d < 32; ++d) s = fmaf(r[d], r[d], s);
  ws_f[WS_CBSQ + i] = s;
}

__device__ __forceinline__ float wsum64(float v) {
#pragma unroll
  for (int m = 32; m >= 1; m >>= 1) v += __shfl_xor(v, m, 64);
  return v;
}

__device__ __forceinline__ float uread(float v) {
  // wave-uniform value -> SGPR (exact; all lanes hold the same bits)
  return __int_as_float(__builtin_amdgcn_readfirstlane(__float_as_int(v)));
}

// main: 256 blocks (8 c x 32 n-blocks), 1024 threads (16 waves), 152.5KB LDS.
// R3: two-pass K-sweep fits 128 VGPR (no scratch). R4: NB=2 n-batching.
// R5/R6 forensics: with EXTERN (dynamic) LDS the compiler can't see the
// 152.5KB and assumes 2 blocks/CU can be co-resident -> occupancy heuristic
// budgets VGPR = pool/(2*wg_waves_per_eu): 128 @512thr, 64 @1024thr.
// waves_per_eu / launch_bounds only CAP registers (min-occupancy bound),
// they never raise the budget -> every "request 128+" was silently lost,
// and the 64-budget force-spilled ~330MB of scratch.
// R7 fix: STATIC __shared__ makes the LDS visible -> occupancy calc proves
// 1 block/CU -> 16 waves/CU = 4 waves/EU -> budget 512/4 = 128, the
// R4-proven no-spill budget, now at 2x R4's latency hiding.
#define ZLD 33               // z_lds leading dim (+1 pad: write stride 33)
__global__ __launch_bounds__(1024, 4)
void k_main(
    const float* __restrict__ z, const float* __restrict__ cb,
    float* __restrict__ out, float* __restrict__ ws_f, int* __restrict__ ws_i) {
  // 39040 floats = 156160 B static LDS (<= 163840 on gfx950)
  __shared__ __attribute__((aligned(16))) float smem[39040];
  float* cb_lds   = smem;              // 32768 floats, xor-swizzled quads
  float* qsum     = smem + 32768;      // 1024 floats: per-block sum_n q
  float* cbsq_lds = smem + 33792;      // 1024 floats: ||cb[c,k]||^2
  float* z_lds    = smem + 34816;      // 128*33 floats: z[nl, d] (padded)

  const int c    = blockIdx.x >> 5;
  const int nblk = blockIdx.x & 31;
  const int tid  = threadIdx.x;
  const int lane = tid & 63;
  const int wave = tid >> 6;           // 0..15

  const int bb   = (nblk * 128) >> 10;      // batch index, constant per block
  const int hwb  = (nblk * 128) & 1023;     // hw base, constant per block

  // ---- stage full channel codebook into LDS, quad-xor swizzle -------------
  const float4* cb4 = (const float4*)(cb + (size_t)c * 32768);
  float4* lds4 = (float4*)cb_lds;
#pragma unroll
  for (int i = 0; i < 8; ++i) {
    int idx = i * 1024 + tid;           // float4 index 0..8191
    int k = idx >> 3, q = idx & 7;
    lds4[(k << 3) + (q ^ (k & 7))] = cb4[idx];
  }
  qsum[tid] = 0.f;
  cbsq_lds[tid] = ws_f[WS_CBSQ + c * 1024 + tid];
  // z slice: 128 n x 32 d, coalesced global reads, padded LDS writes
  {
    const float* zbase = z + (((size_t)bb * 256 + c * 32) << 10) + hwb;
#pragma unroll
    for (int i = 0; i < 4; ++i) {
      int idx = i * 1024 + tid;         // 0..4095
      int d = idx >> 7, j = idx & 127;
      z_lds[j * ZLD + d] = zbase[(size_t)d * 1024 + j];
    }
  }
  __syncthreads();

  float* out_q   = out + OUT_Q;
  float* out_idx = out + OUT_IDX;

  float accA0 = 0.f, accA1 = 0.f, accA2 = 0.f;
  const int kl7 = lane & 7;

#pragma unroll 1
  for (int pp = 0; pp < 4; ++pp) {      // each wave: 4 pairs of n
    const int nl0 = wave * 8 + pp * 2;  // local n in [0,128)
    const int nl1 = nl0 + 1;
    const int n0 = nblk * 128 + nl0;
    const int n1 = n0 + 1;

    // wave-uniform z (LDS broadcast) -> force into SGPRs
    float zv0[32], zv1[32];
#pragma unroll
    for (int d = 0; d < 32; ++d) {
      zv0[d] = uread(z_lds[nl0 * ZLD + d]);
      zv1[d] = uread(z_lds[nl1 * ZLD + d]);
    }
    float zs0 = 0.f, zs1 = 0.f;
#pragma unroll
    for (int d = 0; d < 32; ++d) {
      zs0 = fmaf(zv0[d], zv0[d], zs0);
      zs1 = fmaf(zv1[d], zv1[d], zs1);
    }

    // ---- pass 1: streaming dot for both n -> e, S, es, argmax -------------
    float e0[16], e1[16];
    float S0 = 0.f, S1 = 0.f, es0 = 0.f, es1 = 0.f;
    float sm0 = -INFINITY, sm1 = -INFINITY;
    int km0 = 0, km1 = 0;

#pragma unroll 2
    for (int jj = 0; jj < 16; ++jj) {   // k = jj*64 + lane, covers K=1024
      const int k = jj * 64 + lane;
      float cq = cbsq_lds[k];
      float a0 = 0.f, a1 = 0.f, a2 = 0.f, a3 = 0.f;
      float g0 = 0.f, g1 = 0.f, g2 = 0.f, g3 = 0.f;
#pragma unroll
      for (int q = 0; q < 8; ++q) {
        float4 r4 = lds4[(k << 3) + (q ^ kl7)];
        a0 = fmaf(r4.x, zv0[q * 4 + 0], a0);
        a1 = fmaf(r4.y, zv0[q * 4 + 1], a1);
        a2 = fmaf(r4.z, zv0[q * 4 + 2], a2);
        a3 = fmaf(r4.w, zv0[q * 4 + 3], a3);
        g0 = fmaf(r4.x, zv1[q * 4 + 0], g0);
        g1 = fmaf(r4.y, zv1[q * 4 + 1], g1);
        g2 = fmaf(r4.z, zv1[q * 4 + 2], g2);
        g3 = fmaf(r4.w, zv1[q * 4 + 3], g3);
      }
      float s0 = (a0 + a1) + (a2 + a3) - 0.5f * cq;  // logits + const(n)
      float s1 = (g0 + g1) + (g2 + g3) - 0.5f * cq;
      float ev0 = __expf(s0), ev1 = __expf(s1);
      e0[jj] = ev0; e1[jj] = ev1;
      S0 += ev0;  S1 += ev1;
      es0 = fmaf(ev0, s0, es0);
      es1 = fmaf(ev1, s1, es1);
      if (s0 > sm0) { sm0 = s0; km0 = k; }
      if (s1 > sm1) { sm1 = s1; km1 = k; }
    }

    float St0 = wsum64(S0), St1 = wsum64(S1);
    float rS0 = 1.f / St0, rS1 = 1.f / St1;
    float est0 = wsum64(es0), est1 = wsum64(es1);

    accA1 += (zs0 - 2.f * est0 * rS0) + (zs1 - 2.f * est1 * rS1);
    accA2 += (est0 * rS0 - __logf(St0)) + (est1 * rS1 - __logf(St1));

    // ---- argmax(s) == argmin(dist), tie -> lower k; retire sm/km early ----
#pragma unroll
    for (int m = 32; m >= 1; m >>= 1) {
      float so = __shfl_xor(sm0, m, 64); int ko = __shfl_xor(km0, m, 64);
      if (so > sm0 || (so == sm0 && ko < km0)) { sm0 = so; km0 = ko; }
      float sp = __shfl_xor(sm1, m, 64); int kp = __shfl_xor(km1, m, 64);
      if (sp > sm1 || (sp == sm1 && kp < km1)) { sm1 = sp; km1 = kp; }
    }
    if (lane == 0) {
      out_idx[(size_t)bb * 8192 + c * 1024 + hwb + nl0] = (float)km0;
      ws_i[WS_IDX + n0 * 8 + c] = km0;
      out_idx[(size_t)bb * 8192 + c * 1024 + hwb + nl1] = (float)km1;
      ws_i[WS_IDX + n1 * 8 + c] = km1;
    }

    // ---- pass 2a: e -> qv (in place), q writes, q_bar LDS atomics ---------
    float* qp0 = out_q + ((size_t)n0 * 8 + c) * 1024;
    float* qp1 = out_q + ((size_t)n1 * 8 + c) * 1024;
#pragma unroll 2
    for (int jj = 0; jj < 16; ++jj) {
      float qv0 = e0[jj] * rS0;
      float qv1 = e1[jj] * rS1;
      e0[jj] = qv0; e1[jj] = qv1;
      __builtin_nontemporal_store(qv0, qp0 + jj * 64 + lane);
      __builtin_nontemporal_store(qv1, qp1 + jj * 64 + lane);
      atomicAdd(&qsum[jj * 64 + lane], qv0 + qv1);
    }

    // ---- pass 2b: re-read LDS rows; zq accumulation for both n ------------
    float zq0[32], zq1[32];
#pragma unroll
    for (int d = 0; d < 32; ++d) { zq0[d] = 0.f; zq1[d] = 0.f; }
#pragma unroll 2
    for (int jj = 0; jj < 16; ++jj) {
      const int k = jj * 64 + lane;
      float qv0 = e0[jj], qv1 = e1[jj];
#pragma unroll
      for (int q = 0; q < 8; ++q) {
        float4 r4 = lds4[(k << 3) + (q ^ kl7)];
        zq0[q * 4 + 0] = fmaf(qv0, r4.x, zq0[q * 4 + 0]);
        zq0[q * 4 + 1] = fmaf(qv0, r4.y, zq0[q * 4 + 1]);
        zq0[q * 4 + 2] = fmaf(qv0, r4.z, zq0[q * 4 + 2]);
        zq0[q * 4 + 3] = fmaf(qv0, r4.w, zq0[q * 4 + 3]);
        zq1[q * 4 + 0] = fmaf(qv1, r4.x, zq1[q * 4 + 0]);
        zq1[q * 4 + 1] = fmaf(qv1, r4.y, zq1[q * 4 + 1]);
        zq1[q * 4 + 2] = fmaf(qv1, r4.z, zq1[q * 4 + 2]);
        zq1[q * 4 + 3] = fmaf(qv1, r4.w, zq1[q * 4 + 3]);
      }
    }

    // ---- split-butterfly reduce zq over 64 lanes; lane -> dd=(lane>>1)&31 --
#pragma unroll
    for (int t = 0; t < 5; ++t) {
      const int half = 16 >> t;
      const int up = (lane >> (5 - t)) & 1;
#pragma unroll
      for (int i = 0; i < half; ++i) {
        float sa0 = up ? zq0[i] : zq0[i + half];
        float ka0 = up ? zq0[i + half] : zq0[i];
        zq0[i] = ka0 + __shfl_xor(sa0, 32 >> t, 64);
        float sa1 = up ? zq1[i] : zq1[i + half];
        float ka1 = up ? zq1[i + half] : zq1[i];
        zq1[i] = ka1 + __shfl_xor(sa1, 32 >> t, 64);
      }
    }
    zq0[0] += __shfl_xor(zq0[0], 1, 64);
    zq1[0] += __shfl_xor(zq1[0], 1, 64);
    const int ddl = (lane >> 1) & 31;
    float zf0 = z_lds[nl0 * ZLD + ddl];
    float zf1 = z_lds[nl1 * ZLD + ddl];
    float d0 = zf0 - zq0[0];             // zq already normalized (qv = e*rS)
    float d1 = zf1 - zq1[0];
    accA0 += 0.5f * wsum64(d0 * d0 + d1 * d1);  // each dd counted twice
  }

  if (lane == 0) {
    atomicAdd(&ws_f[WS_A0], accA0);
    atomicAdd(&ws_f[WS_A1], accA1);
    atomicAdd(&ws_f[WS_A2], accA2);
  }

  // ---- q_bar: block LDS accumulator -> global -----------------------------
  __syncthreads();
  atomicAdd(&ws_f[WS_QBAR + c * 1024 + tid], qsum[tid]);
}

// hard-quantized gather: coalesced writes of cb[c, idx[n,c], dd]
__global__ __launch_bounds__(256) void k_hard(const float* __restrict__ cb,
                                              const int* __restrict__ ws_i,
                                              float* __restrict__ out0) {
  int o = blockIdx.x * 256 + threadIdx.x;    // (b, ch, hw) row-major
  int b  = o >> 18;
  int r  = o & 262143;
  int ch = r >> 10;
  int hw = r & 1023;
  int c = ch >> 5, dd = ch & 31;
  int n = (b << 10) + hw;
  int k = ws_i[WS_IDX + n * 8 + c];
  out0[o] = cb[((size_t)(c << 10) + k) * 32 + dd];
}

__global__ __launch_bounds__(256) void k_final(const float* __restrict__ ws_f,
                                               float* __restrict__ out_s) {
  __shared__ float red[256];
  int tid = threadIdx.x;
  float bal = 0.f;
  for (int i = tid; i < 8192; i += 256) {
    float qb = ws_f[WS_QBAR + i] * (1.0f / 4096.0f);
    bal += qb * __logf(qb * 1024.0f + 1e-8f);
  }
  red[tid] = bal;
  __syncthreads();
  for (int s = 128; s > 0; s >>= 1) {
    if (tid < s) red[tid] += red[tid + s];
    __syncthreads();
  }
  if (tid == 0) {
    float A0 = ws_f[WS_A0], A1 = ws_f[WS_A1], A2 = ws_f[WS_A2];
    out_s[0] = A0 * (1.0f / 1048576.0f);                              // commitment
    out_s[1] = (0.5f * A1 + A2) * (1.0f / 32768.0f) + 6.93147180559945f; // free_energy
    out_s[2] = -A2 * (1.0f / 32768.0f);                               // confidence
    out_s[3] = red[0] * 0.125f;                                       // balance
    out_s[4] = 1.0f;                                                  // tau
  }
}

extern "C" void kernel_launch(void* const* d_in, const int* in_sizes, int n_in,
                              void* d_out, int out_size, void* d_ws, size_t ws_size,
                              hipStream_t stream) {
  (void)in_sizes; (void)n_in; (void)out_size; (void)ws_size;
  const float* z  = (const float*)d_in[0];
  const float* cb = (const float*)d_in[1];
  float* out  = (float*)d_out;
  float* ws_f = (float*)d_ws;
  int*   ws_i = (int*)d_ws;

  hipMemsetAsync(d_ws, 0, (WS_QBAR + 8192) * sizeof(float), stream);
  k_cbsq <<<32,   256, 0, stream>>>(cb, ws_f);
  k_main <<<256, 1024, 0, stream>>>(z, cb, out, ws_f, ws_i);
  k_hard <<<4096, 256, 0, stream>>>(cb, ws_i, out);
  k_final<<<1,    256, 0, stream>>>(ws_f, out + OUT_SCAL);
}

// Round 6
// 504.669 us; speedup vs baseline: 1.1023x; 1.0159x over previous
//
#include <hip/hip_runtime.h>

// ---------------- workspace layout (float/int indices into d_ws) ----------
#define WS_A0 0              // commitment sum
#define WS_A1 1              // sum of E_dist over (n,c)
#define WS_A2 2              // sum of neg_ent over (n,c)
#define WS_QBAR 16           // 8192 floats: sum_n q[n,c,k]
#define WS_CBSQ (WS_QBAR + 8192)   // 8192 floats: ||cb[c,k]||^2
#define WS_IDX  (WS_CBSQ + 8192)   // 32768 ints: argmin index per (n,c)

// ---------------- output layout (floats) ----------------------------------
#define OUT_IDX  1048576     // indices (B,C,H,W) as float
#define OUT_Q    1081344     // q (N,C,K)
#define OUT_SCAL 34635776    // commitment, free_energy, confidence, balance, tau

__global__ __launch_bounds__(256) void k_cbsq(const float* __restrict__ cb,
                                              float* __restrict__ ws_f) {
  int i = blockIdx.x * 256 + threadIdx.x;   // 0..8191  (= c*1024 + k)
  const float* r = cb + (size_t)i * 32;
  float s = 0.f;
#pragma unroll
  for (int d = 0; d < 32; ++d) s = fmaf(r[d], r[d], s);
  ws_f[WS_CBSQ + i] = s;
}

__device__ __forceinline__ float wsum64(float v) {
#pragma unroll
  for (int m = 32; m >= 1; m >>= 1) v += __shfl_xor(v, m, 64);
  return v;
}

__device__ __forceinline__ float uread(float v) {
  // wave-uniform value -> SGPR (exact; all lanes hold the same bits)
  return __int_as_float(__builtin_amdgcn_readfirstlane(__float_as_int(v)));
}

// main: 256 blocks (8 c x 32 n-blocks), 1024 threads (16 waves), 152.5KB LDS.
// R5-R7 forensics: at 1024-thr workgroups the backend pins the VGPR budget
// at 64 no matter what (waves_per_eu, launch_bounds min-occ, static LDS all
// tried) -> any >64-reg working set force-spills ~300MB scratch.
// R8: design the loop to be 64-VGPR-NATIVE instead of fighting the
// allocator. Pass 2b's zq0[32]+zq1[32] (=64 regs alone) is split by d into
// two half-sweeps (zqA[16]x2 each, reading only 4 of 8 quads per row ->
// total LDS volume unchanged at 128 reads/n), and the e[16]x2 arrays are
// NOT kept live across pass 2 -- q is re-read from global (regular cached
// stores in pass 2a; the pair's 16KB window is L2-resident on reload).
// Peak live: pass1 ~60, pass2b ~48. First config with budget >= working
// set AND 4 waves/SIMD (16 waves, 1 block/CU).
#define ZLD 33               // z_lds leading dim (+1 pad: write stride 33)
__global__ __launch_bounds__(1024, 4)
void k_main(
    const float* __restrict__ z, const float* __restrict__ cb,
    float* __restrict__ out, float* __restrict__ ws_f, int* __restrict__ ws_i) {
  // 39040 floats = 156160 B static LDS (<= 163840 on gfx950)
  __shared__ __attribute__((aligned(16))) float smem[39040];
  float* cb_lds   = smem;              // 32768 floats, xor-swizzled quads
  float* qsum     = smem + 32768;      // 1024 floats: per-block sum_n q
  float* cbsq_lds = smem + 33792;      // 1024 floats: ||cb[c,k]||^2
  float* z_lds    = smem + 34816;      // 128*33 floats: z[nl, d] (padded)

  const int c    = blockIdx.x >> 5;
  const int nblk = blockIdx.x & 31;
  const int tid  = threadIdx.x;
  const int lane = tid & 63;
  const int wave = tid >> 6;           // 0..15

  const int bb   = (nblk * 128) >> 10;      // batch index, constant per block
  const int hwb  = (nblk * 128) & 1023;     // hw base, constant per block

  // ---- stage full channel codebook into LDS, quad-xor swizzle -------------
  const float4* cb4 = (const float4*)(cb + (size_t)c * 32768);
  float4* lds4 = (float4*)cb_lds;
#pragma unroll
  for (int i = 0; i < 8; ++i) {
    int idx = i * 1024 + tid;           // float4 index 0..8191
    int k = idx >> 3, q = idx & 7;
    lds4[(k << 3) + (q ^ (k & 7))] = cb4[idx];
  }
  qsum[tid] = 0.f;
  cbsq_lds[tid] = ws_f[WS_CBSQ + c * 1024 + tid];
  // z slice: 128 n x 32 d, coalesced global reads, padded LDS writes
  {
    const float* zbase = z + (((size_t)bb * 256 + c * 32) << 10) + hwb;
#pragma unroll
    for (int i = 0; i < 4; ++i) {
      int idx = i * 1024 + tid;         // 0..4095
      int d = idx >> 7, j = idx & 127;
      z_lds[j * ZLD + d] = zbase[(size_t)d * 1024 + j];
    }
  }
  __syncthreads();

  float* out_q   = out + OUT_Q;
  float* out_idx = out + OUT_IDX;

  float accA0 = 0.f, accA1 = 0.f, accA2 = 0.f;
  const int kl7 = lane & 7;

#pragma unroll 1
  for (int pp = 0; pp < 4; ++pp) {      // each wave: 4 pairs of n
    const int nl0 = wave * 8 + pp * 2;  // local n in [0,128)
    const int nl1 = nl0 + 1;
    const int n0 = nblk * 128 + nl0;
    const int n1 = n0 + 1;

    // wave-uniform z (LDS broadcast) -> force into SGPRs
    float zv0[32], zv1[32];
#pragma unroll
    for (int d = 0; d < 32; ++d) {
      zv0[d] = uread(z_lds[nl0 * ZLD + d]);
      zv1[d] = uread(z_lds[nl1 * ZLD + d]);
    }
    float zs0 = 0.f, zs1 = 0.f;
#pragma unroll
    for (int d = 0; d < 32; ++d) {
      zs0 = fmaf(zv0[d], zv0[d], zs0);
      zs1 = fmaf(zv1[d], zv1[d], zs1);
    }

    // ---- pass 1: streaming dot for both n -> e, S, es, argmax -------------
    // 2 dot accumulators per n (not 4): saves 4 regs, pass-1 peak ~60.
    float e0[16], e1[16];
    float S0 = 0.f, S1 = 0.f, es0 = 0.f, es1 = 0.f;
    float sm0 = -INFINITY, sm1 = -INFINITY;
    int km0 = 0, km1 = 0;

#pragma unroll 2
    for (int jj = 0; jj < 16; ++jj) {   // k = jj*64 + lane, covers K=1024
      const int k = jj * 64 + lane;
      float cq = cbsq_lds[k];
      float a0 = 0.f, a1 = 0.f;
      float g0 = 0.f, g1 = 0.f;
#pragma unroll
      for (int q = 0; q < 8; ++q) {
        float4 r4 = lds4[(k << 3) + (q ^ kl7)];
        a0 = fmaf(r4.x, zv0[q * 4 + 0], a0);
        a1 = fmaf(r4.y, zv0[q * 4 + 1], a1);
        a0 = fmaf(r4.z, zv0[q * 4 + 2], a0);
        a1 = fmaf(r4.w, zv0[q * 4 + 3], a1);
        g0 = fmaf(r4.x, zv1[q * 4 + 0], g0);
        g1 = fmaf(r4.y, zv1[q * 4 + 1], g1);
        g0 = fmaf(r4.z, zv1[q * 4 + 2], g0);
        g1 = fmaf(r4.w, zv1[q * 4 + 3], g1);
      }
      float s0 = (a0 + a1) - 0.5f * cq;  // logits + const(n)
      float s1 = (g0 + g1) - 0.5f * cq;
      float ev0 = __expf(s0), ev1 = __expf(s1);
      e0[jj] = ev0; e1[jj] = ev1;
      S0 += ev0;  S1 += ev1;
      es0 = fmaf(ev0, s0, es0);
      es1 = fmaf(ev1, s1, es1);
      if (s0 > sm0) { sm0 = s0; km0 = k; }
      if (s1 > sm1) { sm1 = s1; km1 = k; }
    }

    float St0 = wsum64(S0), St1 = wsum64(S1);
    float rS0 = 1.f / St0, rS1 = 1.f / St1;
    float est0 = wsum64(es0), est1 = wsum64(es1);

    accA1 += (zs0 - 2.f * est0 * rS0) + (zs1 - 2.f * est1 * rS1);
    accA2 += (est0 * rS0 - __logf(St0)) + (est1 * rS1 - __logf(St1));

    // ---- argmax(s) == argmin(dist), tie -> lower k ------------------------
#pragma unroll
    for (int m = 32; m >= 1; m >>= 1) {
      float so = __shfl_xor(sm0, m, 64); int ko = __shfl_xor(km0, m, 64);
      if (so > sm0 || (so == sm0 && ko < km0)) { sm0 = so; km0 = ko; }
      float sp = __shfl_xor(sm1, m, 64); int kp = __shfl_xor(km1, m, 64);
      if (sp > sm1 || (sp == sm1 && kp < km1)) { sm1 = sp; km1 = kp; }
    }
    if (lane == 0) {
      out_idx[(size_t)bb * 8192 + c * 1024 + hwb + nl0] = (float)km0;
      ws_i[WS_IDX + n0 * 8 + c] = km0;
      out_idx[(size_t)bb * 8192 + c * 1024 + hwb + nl1] = (float)km1;
      ws_i[WS_IDX + n1 * 8 + c] = km1;
    }

    // ---- pass 2a: q writes (cached, reloaded below) + q_bar atomics -------
    float* qp0 = out_q + ((size_t)n0 * 8 + c) * 1024;
    float* qp1 = out_q + ((size_t)n1 * 8 + c) * 1024;
#pragma unroll 2
    for (int jj = 0; jj < 16; ++jj) {
      float qv0 = e0[jj] * rS0;
      float qv1 = e1[jj] * rS1;
      qp0[jj * 64 + lane] = qv0;
      qp1[jj * 64 + lane] = qv1;
      atomicAdd(&qsum[jj * 64 + lane], qv0 + qv1);
    }
    // e0/e1 dead here: pass 2b reloads q from global (L2-hot window).

    // ---- pass 2b-A: d = 0..15 (quads 0..3), zq half-accumulate ------------
    float dA0, dA1;
    {
      float zqA0[16], zqA1[16];
#pragma unroll
      for (int i = 0; i < 16; ++i) { zqA0[i] = 0.f; zqA1[i] = 0.f; }
#pragma unroll 2
      for (int jj = 0; jj < 16; ++jj) {
        const int k = jj * 64 + lane;
        float qv0 = qp0[jj * 64 + lane];
        float qv1 = qp1[jj * 64 + lane];
#pragma unroll
        for (int q = 0; q < 4; ++q) {
          float4 r4 = lds4[(k << 3) + (q ^ kl7)];
          zqA0[q * 4 + 0] = fmaf(qv0, r4.x, zqA0[q * 4 + 0]);
          zqA0[q * 4 + 1] = fmaf(qv0, r4.y, zqA0[q * 4 + 1]);
          zqA0[q * 4 + 2] = fmaf(qv0, r4.z, zqA0[q * 4 + 2]);
          zqA0[q * 4 + 3] = fmaf(qv0, r4.w, zqA0[q * 4 + 3]);
          zqA1[q * 4 + 0] = fmaf(qv1, r4.x, zqA1[q * 4 + 0]);
          zqA1[q * 4 + 1] = fmaf(qv1, r4.y, zqA1[q * 4 + 1]);
          zqA1[q * 4 + 2] = fmaf(qv1, r4.z, zqA1[q * 4 + 2]);
          zqA1[q * 4 + 3] = fmaf(qv1, r4.w, zqA1[q * 4 + 3]);
        }
      }
      // 16-value split-butterfly: 4 split steps (xor 32,16,8,4) + 2 folds
#pragma unroll
      for (int t = 0; t < 4; ++t) {
        const int half = 8 >> t;
        const int up = (lane >> (5 - t)) & 1;
#pragma unroll
        for (int i = 0; i < half; ++i) {
          float sa0 = up ? zqA0[i] : zqA0[i + half];
          float ka0 = up ? zqA0[i + half] : zqA0[i];
          zqA0[i] = ka0 + __shfl_xor(sa0, 32 >> t, 64);
          float sa1 = up ? zqA1[i] : zqA1[i + half];
          float ka1 = up ? zqA1[i + half] : zqA1[i];
          zqA1[i] = ka1 + __shfl_xor(sa1, 32 >> t, 64);
        }
      }
      zqA0[0] += __shfl_xor(zqA0[0], 2, 64);
      zqA0[0] += __shfl_xor(zqA0[0], 1, 64);
      zqA1[0] += __shfl_xor(zqA1[0], 2, 64);
      zqA1[0] += __shfl_xor(zqA1[0], 1, 64);
      const int ddA = (lane >> 2) & 15;       // d = ddA, 4 lanes per d
      dA0 = z_lds[nl0 * ZLD + ddA] - zqA0[0];
      dA1 = z_lds[nl1 * ZLD + ddA] - zqA1[0];
    }

    // ---- pass 2b-B: d = 16..31 (quads 4..7) -------------------------------
    float dB0, dB1;
    {
      float zqB0[16], zqB1[16];
#pragma unroll
      for (int i = 0; i < 16; ++i) { zqB0[i] = 0.f; zqB1[i] = 0.f; }
#pragma unroll 2
      for (int jj = 0; jj < 16; ++jj) {
        const int k = jj * 64 + lane;
        float qv0 = qp0[jj * 64 + lane];
        float qv1 = qp1[jj * 64 + lane];
#pragma unroll
        for (int q = 4; q < 8; ++q) {
          float4 r4 = lds4[(k << 3) + (q ^ kl7)];
          const int i0 = (q - 4) * 4;
          zqB0[i0 + 0] = fmaf(qv0, r4.x, zqB0[i0 + 0]);
          zqB0[i0 + 1] = fmaf(qv0, r4.y, zqB0[i0 + 1]);
          zqB0[i0 + 2] = fmaf(qv0, r4.z, zqB0[i0 + 2]);
          zqB0[i0 + 3] = fmaf(qv0, r4.w, zqB0[i0 + 3]);
          zqB1[i0 + 0] = fmaf(qv1, r4.x, zqB1[i0 + 0]);
          zqB1[i0 + 1] = fmaf(qv1, r4.y, zqB1[i0 + 1]);
          zqB1[i0 + 2] = fmaf(qv1, r4.z, zqB1[i0 + 2]);
          zqB1[i0 + 3] = fmaf(qv1, r4.w, zqB1[i0 + 3]);
        }
      }
#pragma unroll
      for (int t = 0; t < 4; ++t) {
        const int half = 8 >> t;
        const int up = (lane >> (5 - t)) & 1;
#pragma unroll
        for (int i = 0; i < half; ++i) {
          float sa0 = up ? zqB0[i] : zqB0[i + half];
          float ka0 = up ? zqB0[i + half] : zqB0[i];
          zqB0[i] = ka0 + __shfl_xor(sa0, 32 >> t, 64);
          float sa1 = up ? zqB1[i] : zqB1[i + half];
          float ka1 = up ? zqB1[i + half] : zqB1[i];
          zqB1[i] = ka1 + __shfl_xor(sa1, 32 >> t, 64);
        }
      }
      zqB0[0] += __shfl_xor(zqB0[0], 2, 64);
      zqB0[0] += __shfl_xor(zqB0[0], 1, 64);
      zqB1[0] += __shfl_xor(zqB1[0], 2, 64);
      zqB1[0] += __shfl_xor(zqB1[0], 1, 64);
      const int ddB = (lane >> 2) & 15;       // d = 16 + ddB
      dB0 = z_lds[nl0 * ZLD + 16 + ddB] - zqB0[0];
      dB1 = z_lds[nl1 * ZLD + 16 + ddB] - zqB1[0];
    }

    // each d counted 4x across lanes -> 0.25
    accA0 += 0.25f * wsum64(dA0 * dA0 + dA1 * dA1 + dB0 * dB0 + dB1 * dB1);
  }

  if (lane == 0) {
    atomicAdd(&ws_f[WS_A0], accA0);
    atomicAdd(&ws_f[WS_A1], accA1);
    atomicAdd(&ws_f[WS_A2], accA2);
  }

  // ---- q_bar: block LDS accumulator -> global -----------------------------
  __syncthreads();
  atomicAdd(&ws_f[WS_QBAR + c * 1024 + tid], qsum[tid]);
}

// hard-quantized gather: coalesced writes of cb[c, idx[n,c], dd]
__global__ __launch_bounds__(256) void k_hard(const float* __restrict__ cb,
                                              const int* __restrict__ ws_i,
                                              float* __restrict__ out0) {
  int o = blockIdx.x * 256 + threadIdx.x;    // (b, ch, hw) row-major
  int b  = o >> 18;
  int r  = o & 262143;
  int ch = r >> 10;
  int hw = r & 1023;
  int c = ch >> 5, dd = ch & 31;
  int n = (b << 10) + hw;
  int k = ws_i[WS_IDX + n * 8 + c];
  out0[o] = cb[((size_t)(c << 10) + k) * 32 + dd];
}

__global__ __launch_bounds__(256) void k_final(const float* __restrict__ ws_f,
                                               float* __restrict__ out_s) {
  __shared__ float red[256];
  int tid = threadIdx.x;
  float bal = 0.f;
  for (int i = tid; i < 8192; i += 256) {
    float qb = ws_f[WS_QBAR + i] * (1.0f / 4096.0f);
    bal += qb * __logf(qb * 1024.0f + 1e-8f);
  }
  red[tid] = bal;
  __syncthreads();
  for (int s = 128; s > 0; s >>= 1) {
    if (tid < s) red[tid] += red[tid + s];
    __syncthreads();
  }
  if (tid == 0) {
    float A0 = ws_f[WS_A0], A1 = ws_f[WS_A1], A2 = ws_f[WS_A2];
    out_s[0] = A0 * (1.0f / 1048576.0f);                              // commitment
    out_s[1] = (0.5f * A1 + A2) * (1.0f / 32768.0f) + 6.93147180559945f; // free_energy
    out_s[2] = -A2 * (1.0f / 32768.0f);                               // confidence
    out_s[3] = red[0] * 0.125f;                                       // balance
    out_s[4] = 1.0f;                                                  // tau
  }
}

extern "C" void kernel_launch(void* const* d_in, const int* in_sizes, int n_in,
                              void* d_out, int out_size, void* d_ws, size_t ws_size,
                              hipStream_t stream) {
  (void)in_sizes; (void)n_in; (void)out_size; (void)ws_size;
  const float* z  = (const float*)d_in[0];
  const float* cb = (const float*)d_in[1];
  float* out  = (float*)d_out;
  float* ws_f = (float*)d_ws;
  int*   ws_i = (int*)d_ws;

  hipMemsetAsync(d_ws, 0, (WS_QBAR + 8192) * sizeof(float), stream);
  k_cbsq <<<32,   256, 0, stream>>>(cb, ws_f);
  k_main <<<256, 1024, 0, stream>>>(z, cb, out, ws_f, ws_i);
  k_hard <<<4096, 256, 0, stream>>>(cb, ws_i, out);
  k_final<<<1,    256, 0, stream>>>(ws_f, out + OUT_SCAL);
}

// Round 7
// 481.738 us; speedup vs baseline: 1.1548x; 1.0476x over previous
//
#include <hip/hip_runtime.h>

// ---------------- workspace layout (float/int indices into d_ws) ----------
#define WS_A0 0              // commitment sum
#define WS_A1 1              // sum of E_dist over (n,c)
#define WS_A2 2              // sum of neg_ent over (n,c)
#define WS_QBAR 16           // 8192 floats: sum_n q[n,c,k]
#define WS_CBSQ (WS_QBAR + 8192)   // 8192 floats: ||cb[c,k]||^2
#define WS_IDX  (WS_CBSQ + 8192)   // 32768 ints: argmin index per (n,c)

// ---------------- output layout (floats) ----------------------------------
#define OUT_IDX  1048576     // indices (B,C,H,W) as float
#define OUT_Q    1081344     // q (N,C,K)
#define OUT_SCAL 34635776    // commitment, free_energy, confidence, balance, tau

__global__ __launch_bounds__(256) void k_cbsq(const float* __restrict__ cb,
                                              float* __restrict__ ws_f) {
  int i = blockIdx.x * 256 + threadIdx.x;   // 0..8191  (= c*1024 + k)
  const float* r = cb + (size_t)i * 32;
  float s = 0.f;
#pragma unroll
  for (int d = 0; d < 32; ++d) s = fmaf(r[d], r[d], s);
  ws_f[WS_CBSQ + i] = s;
}

__device__ __forceinline__ float wsum64(float v) {
#pragma unroll
  for (int m = 32; m >= 1; m >>= 1) v += __shfl_xor(v, m, 64);
  return v;
}

__device__ __forceinline__ float uread(float v) {
  // wave-uniform value -> SGPR (exact; all lanes hold the same bits)
  return __int_as_float(__builtin_amdgcn_readfirstlane(__float_as_int(v)));
}

// main: 256 blocks (8 c x 32 n-blocks), 1024 threads (16 waves), 152.5KB LDS.
// R5-R8 forensics: 1024-thr workgroups pin the VGPR budget at 64 (immutable
// via waves_per_eu / launch_bounds / static LDS). R8's残 spill was pass-1's
// e[32]; its q-reload-from-global missed L2 (~268MB fetch: per-XCD active q
// window == 4MB L2, evicted by the store stream).
// R9: TWO K-sweeps, each ~56-59 regs, NO e[] storage, NO q reloads:
//   sweep1: dot(both n) -> ev=exp(s); S,es; + UNNORMALIZED zqA (d0..15)
//           online (linear in ev; normalized once at butterfly exit).
//   between: wsum S/es -> rS; butterfly A (zqA regs die before sweep2).
//   sweep2: recompute dot (identical fma order -> same s), argmax here,
//           qv=exp(s)*rS, nontemporal q store (write-once), qsum atomic,
//           normalized zqB (d16..31).
// 12 LDS reads/jj/sweep = 384/pair. unroll 1 (MLP from 8 indep quad reads
// + 4 waves/SIMD; unroll-2 only inflates live ranges at a 64-reg budget).
#define ZLD 33               // z_lds leading dim (+1 pad: write stride 33)
__global__ __launch_bounds__(1024, 4)
void k_main(
    const float* __restrict__ z, const float* __restrict__ cb,
    float* __restrict__ out, float* __restrict__ ws_f, int* __restrict__ ws_i) {
  // 39040 floats = 156160 B static LDS (<= 163840 on gfx950)
  __shared__ __attribute__((aligned(16))) float smem[39040];
  float* cb_lds   = smem;              // 32768 floats, xor-swizzled quads
  float* qsum     = smem + 32768;      // 1024 floats: per-block sum_n q
  float* cbsq_lds = smem + 33792;      // 1024 floats: ||cb[c,k]||^2
  float* z_lds    = smem + 34816;      // 128*33 floats: z[nl, d] (padded)

  const int c    = blockIdx.x >> 5;
  const int nblk = blockIdx.x & 31;
  const int tid  = threadIdx.x;
  const int lane = tid & 63;
  const int wave = tid >> 6;           // 0..15

  const int bb   = (nblk * 128) >> 10;      // batch index, constant per block
  const int hwb  = (nblk * 128) & 1023;     // hw base, constant per block

  // ---- stage full channel codebook into LDS, quad-xor swizzle -------------
  const float4* cb4 = (const float4*)(cb + (size_t)c * 32768);
  float4* lds4 = (float4*)cb_lds;
#pragma unroll
  for (int i = 0; i < 8; ++i) {
    int idx = i * 1024 + tid;           // float4 index 0..8191
    int k = idx >> 3, q = idx & 7;
    lds4[(k << 3) + (q ^ (k & 7))] = cb4[idx];
  }
  qsum[tid] = 0.f;
  cbsq_lds[tid] = ws_f[WS_CBSQ + c * 1024 + tid];
  // z slice: 128 n x 32 d, coalesced global reads, padded LDS writes
  {
    const float* zbase = z + (((size_t)bb * 256 + c * 32) << 10) + hwb;
#pragma unroll
    for (int i = 0; i < 4; ++i) {
      int idx = i * 1024 + tid;         // 0..4095
      int d = idx >> 7, j = idx & 127;
      z_lds[j * ZLD + d] = zbase[(size_t)d * 1024 + j];
    }
  }
  __syncthreads();

  float* out_q   = out + OUT_Q;
  float* out_idx = out + OUT_IDX;

  float accA0 = 0.f, accA1 = 0.f, accA2 = 0.f;
  const int kl7 = lane & 7;

#pragma unroll 1
  for (int pp = 0; pp < 4; ++pp) {      // each wave: 4 pairs of n
    const int nl0 = wave * 8 + pp * 2;  // local n in [0,128)
    const int nl1 = nl0 + 1;
    const int n0 = nblk * 128 + nl0;
    const int n1 = n0 + 1;

    // wave-uniform z (LDS broadcast) -> SGPRs
    float zv0[32], zv1[32];
#pragma unroll
    for (int d = 0; d < 32; ++d) {
      zv0[d] = uread(z_lds[nl0 * ZLD + d]);
      zv1[d] = uread(z_lds[nl1 * ZLD + d]);
    }
    float zs0 = 0.f, zs1 = 0.f;
#pragma unroll
    for (int d = 0; d < 32; ++d) {
      zs0 = fmaf(zv0[d], zv0[d], zs0);
      zs1 = fmaf(zv1[d], zv1[d], zs1);
    }

    // ---- sweep 1: dot + S/es + UNNORMALIZED zqA (d 0..15) -----------------
    float S0 = 0.f, S1 = 0.f, es0 = 0.f, es1 = 0.f;
    float zqA0[16], zqA1[16];
#pragma unroll
    for (int i = 0; i < 16; ++i) { zqA0[i] = 0.f; zqA1[i] = 0.f; }

#pragma unroll 1
    for (int jj = 0; jj < 16; ++jj) {   // k = jj*64 + lane, covers K=1024
      const int k = jj * 64 + lane;
      const int kbase = k << 3;
      float a0 = 0.f, a1 = 0.f, g0 = 0.f, g1 = 0.f;
#pragma unroll
      for (int q = 0; q < 8; ++q) {
        float4 r4 = lds4[kbase + (q ^ kl7)];
        a0 = fmaf(r4.x, zv0[q * 4 + 0], a0);
        a1 = fmaf(r4.y, zv0[q * 4 + 1], a1);
        a0 = fmaf(r4.z, zv0[q * 4 + 2], a0);
        a1 = fmaf(r4.w, zv0[q * 4 + 3], a1);
        g0 = fmaf(r4.x, zv1[q * 4 + 0], g0);
        g1 = fmaf(r4.y, zv1[q * 4 + 1], g1);
        g0 = fmaf(r4.z, zv1[q * 4 + 2], g0);
        g1 = fmaf(r4.w, zv1[q * 4 + 3], g1);
      }
      float cq = cbsq_lds[k];
      float s0 = (a0 + a1) - 0.5f * cq;  // logits + const(n)
      float s1 = (g0 + g1) - 0.5f * cq;
      float ev0 = __expf(s0), ev1 = __expf(s1);
      S0 += ev0;  S1 += ev1;
      es0 = fmaf(ev0, s0, es0);
      es1 = fmaf(ev1, s1, es1);
#pragma unroll
      for (int q = 0; q < 4; ++q) {
        float4 r4 = lds4[kbase + (q ^ kl7)];
        zqA0[q * 4 + 0] = fmaf(ev0, r4.x, zqA0[q * 4 + 0]);
        zqA0[q * 4 + 1] = fmaf(ev0, r4.y, zqA0[q * 4 + 1]);
        zqA0[q * 4 + 2] = fmaf(ev0, r4.z, zqA0[q * 4 + 2]);
        zqA0[q * 4 + 3] = fmaf(ev0, r4.w, zqA0[q * 4 + 3]);
        zqA1[q * 4 + 0] = fmaf(ev1, r4.x, zqA1[q * 4 + 0]);
        zqA1[q * 4 + 1] = fmaf(ev1, r4.y, zqA1[q * 4 + 1]);
        zqA1[q * 4 + 2] = fmaf(ev1, r4.z, zqA1[q * 4 + 2]);
        zqA1[q * 4 + 3] = fmaf(ev1, r4.w, zqA1[q * 4 + 3]);
      }
    }

    float St0 = wsum64(S0), St1 = wsum64(S1);
    float rS0 = 1.f / St0, rS1 = 1.f / St1;
    float est0 = wsum64(es0), est1 = wsum64(es1);

    accA1 += (zs0 - 2.f * est0 * rS0) + (zs1 - 2.f * est1 * rS1);
    accA2 += (est0 * rS0 - __logf(St0)) + (est1 * rS1 - __logf(St1));

    // ---- butterfly A now: zqA regs die before sweep 2 ---------------------
    {
#pragma unroll
      for (int t = 0; t < 4; ++t) {
        const int half = 8 >> t;
        const int up = (lane >> (5 - t)) & 1;
#pragma unroll
        for (int i = 0; i < half; ++i) {
          float sa0 = up ? zqA0[i] : zqA0[i + half];
          float ka0 = up ? zqA0[i + half] : zqA0[i];
          zqA0[i] = ka0 + __shfl_xor(sa0, 32 >> t, 64);
          float sa1 = up ? zqA1[i] : zqA1[i + half];
          float ka1 = up ? zqA1[i + half] : zqA1[i];
          zqA1[i] = ka1 + __shfl_xor(sa1, 32 >> t, 64);
        }
      }
      zqA0[0] += __shfl_xor(zqA0[0], 2, 64);
      zqA0[0] += __shfl_xor(zqA0[0], 1, 64);
      zqA1[0] += __shfl_xor(zqA1[0], 2, 64);
      zqA1[0] += __shfl_xor(zqA1[0], 1, 64);
      const int ddA = (lane >> 2) & 15;       // d = ddA, 4 lanes per d
      float dA0 = z_lds[nl0 * ZLD + ddA] - zqA0[0] * rS0;  // normalize here
      float dA1 = z_lds[nl1 * ZLD + ddA] - zqA1[0] * rS1;
      accA0 += 0.25f * wsum64(dA0 * dA0 + dA1 * dA1);  // each d counted 4x
    }

    // ---- sweep 2: recompute dot -> argmax, qv, q store, qsum, zqB ---------
    float sm0 = -INFINITY, sm1 = -INFINITY;
    int km0 = 0, km1 = 0;
    float zqB0[16], zqB1[16];
#pragma unroll
    for (int i = 0; i < 16; ++i) { zqB0[i] = 0.f; zqB1[i] = 0.f; }
    float* qp0 = out_q + ((size_t)n0 * 8 + c) * 1024;
    float* qp1 = out_q + ((size_t)n1 * 8 + c) * 1024;

#pragma unroll 1
    for (int jj = 0; jj < 16; ++jj) {
      const int k = jj * 64 + lane;
      const int kbase = k << 3;
      float a0 = 0.f, a1 = 0.f, g0 = 0.f, g1 = 0.f;
#pragma unroll
      for (int q = 0; q < 8; ++q) {
        float4 r4 = lds4[kbase + (q ^ kl7)];
        a0 = fmaf(r4.x, zv0[q * 4 + 0], a0);
        a1 = fmaf(r4.y, zv0[q * 4 + 1], a1);
        a0 = fmaf(r4.z, zv0[q * 4 + 2], a0);
        a1 = fmaf(r4.w, zv0[q * 4 + 3], a1);
        g0 = fmaf(r4.x, zv1[q * 4 + 0], g0);
        g1 = fmaf(r4.y, zv1[q * 4 + 1], g1);
        g0 = fmaf(r4.z, zv1[q * 4 + 2], g0);
        g1 = fmaf(r4.w, zv1[q * 4 + 3], g1);
      }
      float cq = cbsq_lds[k];
      float s0 = (a0 + a1) - 0.5f * cq;   // identical order -> same s as s1
      float s1 = (g0 + g1) - 0.5f * cq;
      if (s0 > sm0) { sm0 = s0; km0 = k; }
      if (s1 > sm1) { sm1 = s1; km1 = k; }
      float qv0 = __expf(s0) * rS0;
      float qv1 = __expf(s1) * rS1;
      __builtin_nontemporal_store(qv0, qp0 + jj * 64 + lane);
      __builtin_nontemporal_store(qv1, qp1 + jj * 64 + lane);
      atomicAdd(&qsum[jj * 64 + lane], qv0 + qv1);
#pragma unroll
      for (int q = 4; q < 8; ++q) {
        float4 r4 = lds4[kbase + (q ^ kl7)];
        const int i0 = (q - 4) * 4;
        zqB0[i0 + 0] = fmaf(qv0, r4.x, zqB0[i0 + 0]);
        zqB0[i0 + 1] = fmaf(qv0, r4.y, zqB0[i0 + 1]);
        zqB0[i0 + 2] = fmaf(qv0, r4.z, zqB0[i0 + 2]);
        zqB0[i0 + 3] = fmaf(qv0, r4.w, zqB0[i0 + 3]);
        zqB1[i0 + 0] = fmaf(qv1, r4.x, zqB1[i0 + 0]);
        zqB1[i0 + 1] = fmaf(qv1, r4.y, zqB1[i0 + 1]);
        zqB1[i0 + 2] = fmaf(qv1, r4.z, zqB1[i0 + 2]);
        zqB1[i0 + 3] = fmaf(qv1, r4.w, zqB1[i0 + 3]);
      }
    }

    // ---- argmax(s) == argmin(dist), tie -> lower k ------------------------
#pragma unroll
    for (int m = 32; m >= 1; m >>= 1) {
      float so = __shfl_xor(sm0, m, 64); int ko = __shfl_xor(km0, m, 64);
      if (so > sm0 || (so == sm0 && ko < km0)) { sm0 = so; km0 = ko; }
      float sp = __shfl_xor(sm1, m, 64); int kp = __shfl_xor(km1, m, 64);
      if (sp > sm1 || (sp == sm1 && kp < km1)) { sm1 = sp; km1 = kp; }
    }
    if (lane == 0) {
      out_idx[(size_t)bb * 8192 + c * 1024 + hwb + nl0] = (float)km0;
      ws_i[WS_IDX + n0 * 8 + c] = km0;
      out_idx[(size_t)bb * 8192 + c * 1024 + hwb + nl1] = (float)km1;
      ws_i[WS_IDX + n1 * 8 + c] = km1;
    }

    // ---- butterfly B ------------------------------------------------------
#pragma unroll
    for (int t = 0; t < 4; ++t) {
      const int half = 8 >> t;
      const int up = (lane >> (5 - t)) & 1;
#pragma unroll
      for (int i = 0; i < half; ++i) {
        float sa0 = up ? zqB0[i] : zqB0[i + half];
        float ka0 = up ? zqB0[i + half] : zqB0[i];
        zqB0[i] = ka0 + __shfl_xor(sa0, 32 >> t, 64);
        float sa1 = up ? zqB1[i] : zqB1[i + half];
        float ka1 = up ? zqB1[i + half] : zqB1[i];
        zqB1[i] = ka1 + __shfl_xor(sa1, 32 >> t, 64);
      }
    }
    zqB0[0] += __shfl_xor(zqB0[0], 2, 64);
    zqB0[0] += __shfl_xor(zqB0[0], 1, 64);
    zqB1[0] += __shfl_xor(zqB1[0], 2, 64);
    zqB1[0] += __shfl_xor(zqB1[0], 1, 64);
    const int ddB = (lane >> 2) & 15;       // d = 16 + ddB
    float dB0 = z_lds[nl0 * ZLD + 16 + ddB] - zqB0[0];  // qv already norm'd
    float dB1 = z_lds[nl1 * ZLD + 16 + ddB] - zqB1[0];
    accA0 += 0.25f * wsum64(dB0 * dB0 + dB1 * dB1);
  }

  if (lane == 0) {
    atomicAdd(&ws_f[WS_A0], accA0);
    atomicAdd(&ws_f[WS_A1], accA1);
    atomicAdd(&ws_f[WS_A2], accA2);
  }

  // ---- q_bar: block LDS accumulator -> global -----------------------------
  __syncthreads();
  atomicAdd(&ws_f[WS_QBAR + c * 1024 + tid], qsum[tid]);
}

// hard-quantized gather: coalesced writes of cb[c, idx[n,c], dd]
__global__ __launch_bounds__(256) void k_hard(const float* __restrict__ cb,
                                              const int* __restrict__ ws_i,
                                              float* __restrict__ out0) {
  int o = blockIdx.x * 256 + threadIdx.x;    // (b, ch, hw) row-major
  int b  = o >> 18;
  int r  = o & 262143;
  int ch = r >> 10;
  int hw = r & 1023;
  int c = ch >> 5, dd = ch & 31;
  int n = (b << 10) + hw;
  int k = ws_i[WS_IDX + n * 8 + c];
  out0[o] = cb[((size_t)(c << 10) + k) * 32 + dd];
}

__global__ __launch_bounds__(256) void k_final(const float* __restrict__ ws_f,
                                               float* __restrict__ out_s) {
  __shared__ float red[256];
  int tid = threadIdx.x;
  float bal = 0.f;
  for (int i = tid; i < 8192; i += 256) {
    float qb = ws_f[WS_QBAR + i] * (1.0f / 4096.0f);
    bal += qb * __logf(qb * 1024.0f + 1e-8f);
  }
  red[tid] = bal;
  __syncthreads();
  for (int s = 128; s > 0; s >>= 1) {
    if (tid < s) red[tid] += red[tid + s];
    __syncthreads();
  }
  if (tid == 0) {
    float A0 = ws_f[WS_A0], A1 = ws_f[WS_A1], A2 = ws_f[WS_A2];
    out_s[0] = A0 * (1.0f / 1048576.0f);                              // commitment
    out_s[1] = (0.5f * A1 + A2) * (1.0f / 32768.0f) + 6.93147180559945f; // free_energy
    out_s[2] = -A2 * (1.0f / 32768.0f);                               // confidence
    out_s[3] = red[0] * 0.125f;                                       // balance
    out_s[4] = 1.0f;                                                  // tau
  }
}

extern "C" void kernel_launch(void* const* d_in, const int* in_sizes, int n_in,
                              void* d_out, int out_size, void* d_ws, size_t ws_size,
                              hipStream_t stream) {
  (void)in_sizes; (void)n_in; (void)out_size; (void)ws_size;
  const float* z  = (const float*)d_in[0];
  const float* cb = (const float*)d_in[1];
  float* out  = (float*)d_out;
  float* ws_f = (float*)d_ws;
  int*   ws_i = (int*)d_ws;

  hipMemsetAsync(d_ws, 0, (WS_QBAR + 8192) * sizeof(float), stream);
  k_cbsq <<<32,   256, 0, stream>>>(cb, ws_f);
  k_main <<<256, 1024, 0, stream>>>(z, cb, out, ws_f, ws_i);
  k_hard <<<4096, 256, 0, stream>>>(cb, ws_i, out);
  k_final<<<1,    256, 0, stream>>>(ws_f, out + OUT_SCAL);
}

// Round 8
// 448.426 us; speedup vs baseline: 1.2406x; 1.0743x over previous
//
#include <hip/hip_runtime.h>

// ---------------- workspace layout (float/int indices into d_ws) ----------
#define WS_A0 0              // commitment sum
#define WS_A1 1              // sum of E_dist over (n,c)
#define WS_A2 2              // sum of neg_ent over (n,c)
#define WS_QBAR 16           // 8192 floats: sum_n q[n,c,k]
#define WS_CBSQ (WS_QBAR + 8192)   // (unused since R10; kept for layout)
#define WS_IDX  (WS_CBSQ + 8192)   // 32768 ints: argmin index per (n,c)

// ---------------- output layout (floats) ----------------------------------
#define OUT_IDX  1048576     // indices (B,C,H,W) as float
#define OUT_Q    1081344     // q (N,C,K)
#define OUT_SCAL 34635776    // commitment, free_energy, confidence, balance, tau

__device__ __forceinline__ float wsum64(float v) {
#pragma unroll
  for (int m = 32; m >= 1; m >>= 1) v += __shfl_xor(v, m, 64);
  return v;
}

__device__ __forceinline__ float uread(float v) {
  // wave-uniform value -> SGPR (exact; all lanes hold the same bits)
  return __int_as_float(__builtin_amdgcn_readfirstlane(__float_as_int(v)));
}

// main: 256 blocks (8 c x 32 n-blocks), 1024 threads (16 waves), 152.5KB LDS.
// R9: 64-VGPR-native two-sweep structure (no spill, no q-reload).
// R10: (a) keep-2-quads forwarding -- dot reads quads in order
// [4,5,6,7,0,1,2,3] keeping the last two in registers so the zq re-read
// only touches 2 quads: 24 -> 20 b128/jj/pair (-17% LDS traffic+conflicts).
// (b) cbsq fused into the prologue (computed from staged cb_lds; k_cbsq
// kernel deleted). (c) k_final fused into k_hard block 0. 5 -> 3 launches.
#define ZLD 33               // z_lds leading dim (+1 pad: write stride 33)
__global__ __launch_bounds__(1024, 4)
void k_main(
    const float* __restrict__ z, const float* __restrict__ cb,
    float* __restrict__ out, float* __restrict__ ws_f, int* __restrict__ ws_i) {
  // 39040 floats = 156160 B static LDS (<= 163840 on gfx950)
  __shared__ __attribute__((aligned(16))) float smem[39040];
  float* cb_lds   = smem;              // 32768 floats, xor-swizzled quads
  float* qsum     = smem + 32768;      // 1024 floats: per-block sum_n q
  float* cbsq_lds = smem + 33792;      // 1024 floats: ||cb[c,k]||^2
  float* z_lds    = smem + 34816;      // 128*33 floats: z[nl, d] (padded)

  const int c    = blockIdx.x >> 5;
  const int nblk = blockIdx.x & 31;
  const int tid  = threadIdx.x;
  const int lane = tid & 63;
  const int wave = tid >> 6;           // 0..15

  const int bb   = (nblk * 128) >> 10;      // batch index, constant per block
  const int hwb  = (nblk * 128) & 1023;     // hw base, constant per block

  // ---- stage full channel codebook into LDS, quad-xor swizzle -------------
  const float4* cb4 = (const float4*)(cb + (size_t)c * 32768);
  float4* lds4 = (float4*)cb_lds;
#pragma unroll
  for (int i = 0; i < 8; ++i) {
    int idx = i * 1024 + tid;           // float4 index 0..8191
    int k = idx >> 3, q = idx & 7;
    lds4[(k << 3) + (q ^ (k & 7))] = cb4[idx];
  }
  qsum[tid] = 0.f;
  // z slice: 128 n x 32 d, coalesced global reads, padded LDS writes
  {
    const float* zbase = z + (((size_t)bb * 256 + c * 32) << 10) + hwb;
#pragma unroll
    for (int i = 0; i < 4; ++i) {
      int idx = i * 1024 + tid;         // 0..4095
      int d = idx >> 7, j = idx & 127;
      z_lds[j * ZLD + d] = zbase[(size_t)d * 1024 + j];
    }
  }
  __syncthreads();
  // cbsq from staged rows: slots q^(tid&7) ascending == quads d-ascending
  {
    float s = 0.f;
    const int t7 = tid & 7;
#pragma unroll
    for (int q = 0; q < 8; ++q) {
      float4 r4 = lds4[(tid << 3) + (q ^ t7)];
      s = fmaf(r4.x, r4.x, s); s = fmaf(r4.y, r4.y, s);
      s = fmaf(r4.z, r4.z, s); s = fmaf(r4.w, r4.w, s);
    }
    cbsq_lds[tid] = s;
  }
  __syncthreads();

  float* out_q   = out + OUT_Q;
  float* out_idx = out + OUT_IDX;

  float accA0 = 0.f, accA1 = 0.f, accA2 = 0.f;
  const int kl7 = lane & 7;

#pragma unroll 1
  for (int pp = 0; pp < 4; ++pp) {      // each wave: 4 pairs of n
    const int nl0 = wave * 8 + pp * 2;  // local n in [0,128)
    const int nl1 = nl0 + 1;
    const int n0 = nblk * 128 + nl0;
    const int n1 = n0 + 1;

    // wave-uniform z (LDS broadcast) -> SGPRs
    float zv0[32], zv1[32];
#pragma unroll
    for (int d = 0; d < 32; ++d) {
      zv0[d] = uread(z_lds[nl0 * ZLD + d]);
      zv1[d] = uread(z_lds[nl1 * ZLD + d]);
    }
    float zs0 = 0.f, zs1 = 0.f;
#pragma unroll
    for (int d = 0; d < 32; ++d) {
      zs0 = fmaf(zv0[d], zv0[d], zs0);
      zs1 = fmaf(zv1[d], zv1[d], zs1);
    }

    // ---- sweep 1: dot (keep quads 2,3) + S/es + zqA (d 0..15) -------------
    float S0 = 0.f, S1 = 0.f, es0 = 0.f, es1 = 0.f;
    float zqA0[16], zqA1[16];
#pragma unroll
    for (int i = 0; i < 16; ++i) { zqA0[i] = 0.f; zqA1[i] = 0.f; }

#pragma unroll 1
    for (int jj = 0; jj < 16; ++jj) {   // k = jj*64 + lane, covers K=1024
      const int k = jj * 64 + lane;
      const int kbase = k << 3;
      float a0 = 0.f, a1 = 0.f, g0 = 0.f, g1 = 0.f;
#pragma unroll
      for (int qq = 0; qq < 6; ++qq) {   // q = 4,5,6,7,0,1 (discard)
        const int q = (qq + 4) & 7;
        float4 r4 = lds4[kbase + (q ^ kl7)];
        a0 = fmaf(r4.x, zv0[q * 4 + 0], a0);
        a1 = fmaf(r4.y, zv0[q * 4 + 1], a1);
        a0 = fmaf(r4.z, zv0[q * 4 + 2], a0);
        a1 = fmaf(r4.w, zv0[q * 4 + 3], a1);
        g0 = fmaf(r4.x, zv1[q * 4 + 0], g0);
        g1 = fmaf(r4.y, zv1[q * 4 + 1], g1);
        g0 = fmaf(r4.z, zv1[q * 4 + 2], g0);
        g1 = fmaf(r4.w, zv1[q * 4 + 3], g1);
      }
      float4 kq2 = lds4[kbase + (2 ^ kl7)];   // kept for zqA
      a0 = fmaf(kq2.x, zv0[8], a0);  a1 = fmaf(kq2.y, zv0[9], a1);
      a0 = fmaf(kq2.z, zv0[10], a0); a1 = fmaf(kq2.w, zv0[11], a1);
      g0 = fmaf(kq2.x, zv1[8], g0);  g1 = fmaf(kq2.y, zv1[9], g1);
      g0 = fmaf(kq2.z, zv1[10], g0); g1 = fmaf(kq2.w, zv1[11], g1);
      float4 kq3 = lds4[kbase + (3 ^ kl7)];   // kept for zqA
      a0 = fmaf(kq3.x, zv0[12], a0); a1 = fmaf(kq3.y, zv0[13], a1);
      a0 = fmaf(kq3.z, zv0[14], a0); a1 = fmaf(kq3.w, zv0[15], a1);
      g0 = fmaf(kq3.x, zv1[12], g0); g1 = fmaf(kq3.y, zv1[13], g1);
      g0 = fmaf(kq3.z, zv1[14], g0); g1 = fmaf(kq3.w, zv1[15], g1);

      float cq = cbsq_lds[k];
      float s0 = (a0 + a1) - 0.5f * cq;  // logits + const(n)
      float s1 = (g0 + g1) - 0.5f * cq;
      float ev0 = __expf(s0), ev1 = __expf(s1);
      S0 += ev0;  S1 += ev1;
      es0 = fmaf(ev0, s0, es0);
      es1 = fmaf(ev1, s1, es1);
      // zqA: re-read quads 0,1; consume kept kq2,kq3
#pragma unroll
      for (int q = 0; q < 2; ++q) {
        float4 r4 = lds4[kbase + (q ^ kl7)];
        zqA0[q * 4 + 0] = fmaf(ev0, r4.x, zqA0[q * 4 + 0]);
        zqA0[q * 4 + 1] = fmaf(ev0, r4.y, zqA0[q * 4 + 1]);
        zqA0[q * 4 + 2] = fmaf(ev0, r4.z, zqA0[q * 4 + 2]);
        zqA0[q * 4 + 3] = fmaf(ev0, r4.w, zqA0[q * 4 + 3]);
        zqA1[q * 4 + 0] = fmaf(ev1, r4.x, zqA1[q * 4 + 0]);
        zqA1[q * 4 + 1] = fmaf(ev1, r4.y, zqA1[q * 4 + 1]);
        zqA1[q * 4 + 2] = fmaf(ev1, r4.z, zqA1[q * 4 + 2]);
        zqA1[q * 4 + 3] = fmaf(ev1, r4.w, zqA1[q * 4 + 3]);
      }
      zqA0[8]  = fmaf(ev0, kq2.x, zqA0[8]);  zqA0[9]  = fmaf(ev0, kq2.y, zqA0[9]);
      zqA0[10] = fmaf(ev0, kq2.z, zqA0[10]); zqA0[11] = fmaf(ev0, kq2.w, zqA0[11]);
      zqA1[8]  = fmaf(ev1, kq2.x, zqA1[8]);  zqA1[9]  = fmaf(ev1, kq2.y, zqA1[9]);
      zqA1[10] = fmaf(ev1, kq2.z, zqA1[10]); zqA1[11] = fmaf(ev1, kq2.w, zqA1[11]);
      zqA0[12] = fmaf(ev0, kq3.x, zqA0[12]); zqA0[13] = fmaf(ev0, kq3.y, zqA0[13]);
      zqA0[14] = fmaf(ev0, kq3.z, zqA0[14]); zqA0[15] = fmaf(ev0, kq3.w, zqA0[15]);
      zqA1[12] = fmaf(ev1, kq3.x, zqA1[12]); zqA1[13] = fmaf(ev1, kq3.y, zqA1[13]);
      zqA1[14] = fmaf(ev1, kq3.z, zqA1[14]); zqA1[15] = fmaf(ev1, kq3.w, zqA1[15]);
    }

    float St0 = wsum64(S0), St1 = wsum64(S1);
    float rS0 = 1.f / St0, rS1 = 1.f / St1;
    float est0 = wsum64(es0), est1 = wsum64(es1);

    accA1 += (zs0 - 2.f * est0 * rS0) + (zs1 - 2.f * est1 * rS1);
    accA2 += (est0 * rS0 - __logf(St0)) + (est1 * rS1 - __logf(St1));

    // ---- butterfly A now: zqA regs die before sweep 2 ---------------------
    {
#pragma unroll
      for (int t = 0; t < 4; ++t) {
        const int half = 8 >> t;
        const int up = (lane >> (5 - t)) & 1;
#pragma unroll
        for (int i = 0; i < half; ++i) {
          float sa0 = up ? zqA0[i] : zqA0[i + half];
          float ka0 = up ? zqA0[i + half] : zqA0[i];
          zqA0[i] = ka0 + __shfl_xor(sa0, 32 >> t, 64);
          float sa1 = up ? zqA1[i] : zqA1[i + half];
          float ka1 = up ? zqA1[i + half] : zqA1[i];
          zqA1[i] = ka1 + __shfl_xor(sa1, 32 >> t, 64);
        }
      }
      zqA0[0] += __shfl_xor(zqA0[0], 2, 64);
      zqA0[0] += __shfl_xor(zqA0[0], 1, 64);
      zqA1[0] += __shfl_xor(zqA1[0], 2, 64);
      zqA1[0] += __shfl_xor(zqA1[0], 1, 64);
      const int ddA = (lane >> 2) & 15;       // d = ddA, 4 lanes per d
      float dA0 = z_lds[nl0 * ZLD + ddA] - zqA0[0] * rS0;  // normalize here
      float dA1 = z_lds[nl1 * ZLD + ddA] - zqA1[0] * rS1;
      accA0 += 0.25f * wsum64(dA0 * dA0 + dA1 * dA1);  // each d counted 4x
    }

    // ---- sweep 2: recompute dot (keep 6,7) -> argmax, qv, store, zqB ------
    float sm0 = -INFINITY, sm1 = -INFINITY;
    int km0 = 0, km1 = 0;
    float zqB0[16], zqB1[16];
#pragma unroll
    for (int i = 0; i < 16; ++i) { zqB0[i] = 0.f; zqB1[i] = 0.f; }
    float* qp0 = out_q + ((size_t)n0 * 8 + c) * 1024;
    float* qp1 = out_q + ((size_t)n1 * 8 + c) * 1024;

#pragma unroll 1
    for (int jj = 0; jj < 16; ++jj) {
      const int k = jj * 64 + lane;
      const int kbase = k << 3;
      float a0 = 0.f, a1 = 0.f, g0 = 0.f, g1 = 0.f;
#pragma unroll
      for (int q = 0; q < 6; ++q) {      // q = 0..5 (discard)
        float4 r4 = lds4[kbase + (q ^ kl7)];
        a0 = fmaf(r4.x, zv0[q * 4 + 0], a0);
        a1 = fmaf(r4.y, zv0[q * 4 + 1], a1);
        a0 = fmaf(r4.z, zv0[q * 4 + 2], a0);
        a1 = fmaf(r4.w, zv0[q * 4 + 3], a1);
        g0 = fmaf(r4.x, zv1[q * 4 + 0], g0);
        g1 = fmaf(r4.y, zv1[q * 4 + 1], g1);
        g0 = fmaf(r4.z, zv1[q * 4 + 2], g0);
        g1 = fmaf(r4.w, zv1[q * 4 + 3], g1);
      }
      float4 kq6 = lds4[kbase + (6 ^ kl7)];   // kept for zqB
      a0 = fmaf(kq6.x, zv0[24], a0); a1 = fmaf(kq6.y, zv0[25], a1);
      a0 = fmaf(kq6.z, zv0[26], a0); a1 = fmaf(kq6.w, zv0[27], a1);
      g0 = fmaf(kq6.x, zv1[24], g0); g1 = fmaf(kq6.y, zv1[25], g1);
      g0 = fmaf(kq6.z, zv1[26], g0); g1 = fmaf(kq6.w, zv1[27], g1);
      float4 kq7 = lds4[kbase + (7 ^ kl7)];   // kept for zqB
      a0 = fmaf(kq7.x, zv0[28], a0); a1 = fmaf(kq7.y, zv0[29], a1);
      a0 = fmaf(kq7.z, zv0[30], a0); a1 = fmaf(kq7.w, zv0[31], a1);
      g0 = fmaf(kq7.x, zv1[28], g0); g1 = fmaf(kq7.y, zv1[29], g1);
      g0 = fmaf(kq7.z, zv1[30], g0); g1 = fmaf(kq7.w, zv1[31], g1);

      float cq = cbsq_lds[k];
      float s0 = (a0 + a1) - 0.5f * cq;
      float s1 = (g0 + g1) - 0.5f * cq;
      if (s0 > sm0) { sm0 = s0; km0 = k; }
      if (s1 > sm1) { sm1 = s1; km1 = k; }
      float qv0 = __expf(s0) * rS0;
      float qv1 = __expf(s1) * rS1;
      __builtin_nontemporal_store(qv0, qp0 + jj * 64 + lane);
      __builtin_nontemporal_store(qv1, qp1 + jj * 64 + lane);
      atomicAdd(&qsum[jj * 64 + lane], qv0 + qv1);
      // zqB: re-read quads 4,5; consume kept kq6,kq7  (d = 16 + (q-4)*4 + e)
#pragma unroll
      for (int q = 4; q < 6; ++q) {
        float4 r4 = lds4[kbase + (q ^ kl7)];
        const int i0 = (q - 4) * 4;
        zqB0[i0 + 0] = fmaf(qv0, r4.x, zqB0[i0 + 0]);
        zqB0[i0 + 1] = fmaf(qv0, r4.y, zqB0[i0 + 1]);
        zqB0[i0 + 2] = fmaf(qv0, r4.z, zqB0[i0 + 2]);
        zqB0[i0 + 3] = fmaf(qv0, r4.w, zqB0[i0 + 3]);
        zqB1[i0 + 0] = fmaf(qv1, r4.x, zqB1[i0 + 0]);
        zqB1[i0 + 1] = fmaf(qv1, r4.y, zqB1[i0 + 1]);
        zqB1[i0 + 2] = fmaf(qv1, r4.z, zqB1[i0 + 2]);
        zqB1[i0 + 3] = fmaf(qv1, r4.w, zqB1[i0 + 3]);
      }
      zqB0[8]  = fmaf(qv0, kq6.x, zqB0[8]);  zqB0[9]  = fmaf(qv0, kq6.y, zqB0[9]);
      zqB0[10] = fmaf(qv0, kq6.z, zqB0[10]); zqB0[11] = fmaf(qv0, kq6.w, zqB0[11]);
      zqB1[8]  = fmaf(qv1, kq6.x, zqB1[8]);  zqB1[9]  = fmaf(qv1, kq6.y, zqB1[9]);
      zqB1[10] = fmaf(qv1, kq6.z, zqB1[10]); zqB1[11] = fmaf(qv1, kq6.w, zqB1[11]);
      zqB0[12] = fmaf(qv0, kq7.x, zqB0[12]); zqB0[13] = fmaf(qv0, kq7.y, zqB0[13]);
      zqB0[14] = fmaf(qv0, kq7.z, zqB0[14]); zqB0[15] = fmaf(qv0, kq7.w, zqB0[15]);
      zqB1[12] = fmaf(qv1, kq7.x, zqB1[12]); zqB1[13] = fmaf(qv1, kq7.y, zqB1[13]);
      zqB1[14] = fmaf(qv1, kq7.z, zqB1[14]); zqB1[15] = fmaf(qv1, kq7.w, zqB1[15]);
    }

    // ---- argmax(s) == argmin(dist), tie -> lower k ------------------------
#pragma unroll
    for (int m = 32; m >= 1; m >>= 1) {
      float so = __shfl_xor(sm0, m, 64); int ko = __shfl_xor(km0, m, 64);
      if (so > sm0 || (so == sm0 && ko < km0)) { sm0 = so; km0 = ko; }
      float sp = __shfl_xor(sm1, m, 64); int kp = __shfl_xor(km1, m, 64);
      if (sp > sm1 || (sp == sm1 && kp < km1)) { sm1 = sp; km1 = kp; }
    }
    if (lane == 0) {
      out_idx[(size_t)bb * 8192 + c * 1024 + hwb + nl0] = (float)km0;
      ws_i[WS_IDX + n0 * 8 + c] = km0;
      out_idx[(size_t)bb * 8192 + c * 1024 + hwb + nl1] = (float)km1;
      ws_i[WS_IDX + n1 * 8 + c] = km1;
    }

    // ---- butterfly B ------------------------------------------------------
#pragma unroll
    for (int t = 0; t < 4; ++t) {
      const int half = 8 >> t;
      const int up = (lane >> (5 - t)) & 1;
#pragma unroll
      for (int i = 0; i < half; ++i) {
        float sa0 = up ? zqB0[i] : zqB0[i + half];
        float ka0 = up ? zqB0[i + half] : zqB0[i];
        zqB0[i] = ka0 + __shfl_xor(sa0, 32 >> t, 64);
        float sa1 = up ? zqB1[i] : zqB1[i + half];
        float ka1 = up ? zqB1[i + half] : zqB1[i];
        zqB1[i] = ka1 + __shfl_xor(sa1, 32 >> t, 64);
      }
    }
    zqB0[0] += __shfl_xor(zqB0[0], 2, 64);
    zqB0[0] += __shfl_xor(zqB0[0], 1, 64);
    zqB1[0] += __shfl_xor(zqB1[0], 2, 64);
    zqB1[0] += __shfl_xor(zqB1[0], 1, 64);
    const int ddB = (lane >> 2) & 15;       // d = 16 + ddB
    float dB0 = z_lds[nl0 * ZLD + 16 + ddB] - zqB0[0];  // qv already norm'd
    float dB1 = z_lds[nl1 * ZLD + 16 + ddB] - zqB1[0];
    accA0 += 0.25f * wsum64(dB0 * dB0 + dB1 * dB1);
  }

  if (lane == 0) {
    atomicAdd(&ws_f[WS_A0], accA0);
    atomicAdd(&ws_f[WS_A1], accA1);
    atomicAdd(&ws_f[WS_A2], accA2);
  }

  // ---- q_bar: block LDS accumulator -> global -----------------------------
  __syncthreads();
  atomicAdd(&ws_f[WS_QBAR + c * 1024 + tid], qsum[tid]);
}

// hard-quantized gather (all blocks) + scalar finalization (block 0).
// k_main->k_hard kernel boundary orders all ws_f/ws_i writes.
__global__ __launch_bounds__(256) void k_hard(const float* __restrict__ cb,
                                              const int* __restrict__ ws_i,
                                              float* __restrict__ out0,
                                              const float* __restrict__ ws_f,
                                              float* __restrict__ out_s) {
  int o = blockIdx.x * 256 + threadIdx.x;    // (b, ch, hw) row-major
  int b  = o >> 18;
  int r  = o & 262143;
  int ch = r >> 10;
  int hw = r & 1023;
  int c = ch >> 5, dd = ch & 31;
  int n = (b << 10) + hw;
  int k = ws_i[WS_IDX + n * 8 + c];
  out0[o] = cb[((size_t)(c << 10) + k) * 32 + dd];

  if (blockIdx.x == 0) {                     // block-uniform branch
    __shared__ float red[256];
    int tid = threadIdx.x;
    float bal = 0.f;
    for (int i = tid; i < 8192; i += 256) {
      float qb = ws_f[WS_QBAR + i] * (1.0f / 4096.0f);
      bal += qb * __logf(qb * 1024.0f + 1e-8f);
    }
    red[tid] = bal;
    __syncthreads();
    for (int s = 128; s > 0; s >>= 1) {
      if (tid < s) red[tid] += red[tid + s];
      __syncthreads();
    }
    if (tid == 0) {
      float A0 = ws_f[WS_A0], A1 = ws_f[WS_A1], A2 = ws_f[WS_A2];
      out_s[0] = A0 * (1.0f / 1048576.0f);                              // commitment
      out_s[1] = (0.5f * A1 + A2) * (1.0f / 32768.0f) + 6.93147180559945f; // free_energy
      out_s[2] = -A2 * (1.0f / 32768.0f);                               // confidence
      out_s[3] = red[0] * 0.125f;                                       // balance
      out_s[4] = 1.0f;                                                  // tau
    }
  }
}

extern "C" void kernel_launch(void* const* d_in, const int* in_sizes, int n_in,
                              void* d_out, int out_size, void* d_ws, size_t ws_size,
                              hipStream_t stream) {
  (void)in_sizes; (void)n_in; (void)out_size; (void)ws_size;
  const float* z  = (const float*)d_in[0];
  const float* cb = (const float*)d_in[1];
  float* out  = (float*)d_out;
  float* ws_f = (float*)d_ws;
  int*   ws_i = (int*)d_ws;

  hipMemsetAsync(d_ws, 0, (WS_QBAR + 8192) * sizeof(float), stream);
  k_main <<<256, 1024, 0, stream>>>(z, cb, out, ws_f, ws_i);
  k_hard <<<4096, 256, 0, stream>>>(cb, ws_i, out, ws_f, out + OUT_SCAL);
}

// Round 9
// 436.357 us; speedup vs baseline: 1.2749x; 1.0277x over previous
//
#include <hip/hip_runtime.h>

// ---------------- workspace layout (float/int indices into d_ws) ----------
#define WS_A0 0              // commitment sum
#define WS_A1 1              // sum of E_dist over (n,c)
#define WS_A2 2              // sum of neg_ent over (n,c)
#define WS_QBAR 16           // 8192 floats: sum_n q[n,c,k]
#define WS_CBSQ (WS_QBAR + 8192)   // (unused since R10; kept for layout)
#define WS_IDX  (WS_CBSQ + 8192)   // 32768 ints: argmin index per (n,c)

// ---------------- output layout (floats) ----------------------------------
#define OUT_IDX  1048576     // indices (B,C,H,W) as float
#define OUT_Q    1081344     // q (N,C,K)
#define OUT_SCAL 34635776    // commitment, free_energy, confidence, balance, tau

__device__ __forceinline__ float wsum64(float v) {
#pragma unroll
  for (int m = 32; m >= 1; m >>= 1) v += __shfl_xor(v, m, 64);
  return v;
}

__device__ __forceinline__ float uread(float v) {
  // wave-uniform value -> SGPR (exact; all lanes hold the same bits)
  return __int_as_float(__builtin_amdgcn_readfirstlane(__float_as_int(v)));
}

// main: 256 blocks (8 c x 32 n-blocks), 1024 threads (16 waves), 152.5KB LDS.
// R9: 64-VGPR-native two-sweep structure (no spill, no q-reload).
// R10: keep-2-quads forwarding (20 b128/jj/pair), fused cbsq + final.
// R11: (a) sweep-2 keep-4 -- quads 4..7 held in regs through the dot and
// consumed again by zqB: 10 -> 8 reads/jj (18 total/jj/pair, -10% LDS).
// (b) accA0's per-pair wsum64 deferred (linear): per-lane accumulate,
// single wsum64 after the pp loop (-~120 shuffle ops/pair).
// (c) k_hard float4-vectorized (4 hw per thread).
// Occupancy is structurally capped at 4 waves/SIMD (full 128KB codebook
// residency -> 1 block/CU); remaining gap is read->fma->exp dependency
// latency, not pipe saturation.
#define ZLD 33               // z_lds leading dim (+1 pad: write stride 33)
__global__ __launch_bounds__(1024, 4)
void k_main(
    const float* __restrict__ z, const float* __restrict__ cb,
    float* __restrict__ out, float* __restrict__ ws_f, int* __restrict__ ws_i) {
  // 39040 floats = 156160 B static LDS (<= 163840 on gfx950)
  __shared__ __attribute__((aligned(16))) float smem[39040];
  float* cb_lds   = smem;              // 32768 floats, xor-swizzled quads
  float* qsum     = smem + 32768;      // 1024 floats: per-block sum_n q
  float* cbsq_lds = smem + 33792;      // 1024 floats: ||cb[c,k]||^2
  float* z_lds    = smem + 34816;      // 128*33 floats: z[nl, d] (padded)

  const int c    = blockIdx.x >> 5;
  const int nblk = blockIdx.x & 31;
  const int tid  = threadIdx.x;
  const int lane = tid & 63;
  const int wave = tid >> 6;           // 0..15

  const int bb   = (nblk * 128) >> 10;      // batch index, constant per block
  const int hwb  = (nblk * 128) & 1023;     // hw base, constant per block

  // ---- stage full channel codebook into LDS, quad-xor swizzle -------------
  const float4* cb4 = (const float4*)(cb + (size_t)c * 32768);
  float4* lds4 = (float4*)cb_lds;
#pragma unroll
  for (int i = 0; i < 8; ++i) {
    int idx = i * 1024 + tid;           // float4 index 0..8191
    int k = idx >> 3, q = idx & 7;
    lds4[(k << 3) + (q ^ (k & 7))] = cb4[idx];
  }
  qsum[tid] = 0.f;
  // z slice: 128 n x 32 d, coalesced global reads, padded LDS writes
  {
    const float* zbase = z + (((size_t)bb * 256 + c * 32) << 10) + hwb;
#pragma unroll
    for (int i = 0; i < 4; ++i) {
      int idx = i * 1024 + tid;         // 0..4095
      int d = idx >> 7, j = idx & 127;
      z_lds[j * ZLD + d] = zbase[(size_t)d * 1024 + j];
    }
  }
  __syncthreads();
  // cbsq from staged rows: slots q^(tid&7) ascending == quads d-ascending
  {
    float s = 0.f;
    const int t7 = tid & 7;
#pragma unroll
    for (int q = 0; q < 8; ++q) {
      float4 r4 = lds4[(tid << 3) + (q ^ t7)];
      s = fmaf(r4.x, r4.x, s); s = fmaf(r4.y, r4.y, s);
      s = fmaf(r4.z, r4.z, s); s = fmaf(r4.w, r4.w, s);
    }
    cbsq_lds[tid] = s;
  }
  __syncthreads();

  float* out_q   = out + OUT_Q;
  float* out_idx = out + OUT_IDX;

  float accA1 = 0.f, accA2 = 0.f;
  float a0loc = 0.f;                    // per-lane commitment partial (R11b)
  const int kl7 = lane & 7;

#pragma unroll 1
  for (int pp = 0; pp < 4; ++pp) {      // each wave: 4 pairs of n
    const int nl0 = wave * 8 + pp * 2;  // local n in [0,128)
    const int nl1 = nl0 + 1;
    const int n0 = nblk * 128 + nl0;
    const int n1 = n0 + 1;

    // wave-uniform z (LDS broadcast) -> SGPRs
    float zv0[32], zv1[32];
#pragma unroll
    for (int d = 0; d < 32; ++d) {
      zv0[d] = uread(z_lds[nl0 * ZLD + d]);
      zv1[d] = uread(z_lds[nl1 * ZLD + d]);
    }
    float zs0 = 0.f, zs1 = 0.f;
#pragma unroll
    for (int d = 0; d < 32; ++d) {
      zs0 = fmaf(zv0[d], zv0[d], zs0);
      zs1 = fmaf(zv1[d], zv1[d], zs1);
    }

    // ---- sweep 1: dot (keep quads 2,3) + S/es + zqA (d 0..15) -------------
    float S0 = 0.f, S1 = 0.f, es0 = 0.f, es1 = 0.f;
    float zqA0[16], zqA1[16];
#pragma unroll
    for (int i = 0; i < 16; ++i) { zqA0[i] = 0.f; zqA1[i] = 0.f; }

#pragma unroll 1
    for (int jj = 0; jj < 16; ++jj) {   // k = jj*64 + lane, covers K=1024
      const int k = jj * 64 + lane;
      const int kbase = k << 3;
      float cq = cbsq_lds[k];
      float a0 = 0.f, a1 = 0.f, g0 = 0.f, g1 = 0.f;
#pragma unroll
      for (int qq = 0; qq < 6; ++qq) {   // q = 4,5,6,7,0,1 (discard)
        const int q = (qq + 4) & 7;
        float4 r4 = lds4[kbase + (q ^ kl7)];
        a0 = fmaf(r4.x, zv0[q * 4 + 0], a0);
        a1 = fmaf(r4.y, zv0[q * 4 + 1], a1);
        a0 = fmaf(r4.z, zv0[q * 4 + 2], a0);
        a1 = fmaf(r4.w, zv0[q * 4 + 3], a1);
        g0 = fmaf(r4.x, zv1[q * 4 + 0], g0);
        g1 = fmaf(r4.y, zv1[q * 4 + 1], g1);
        g0 = fmaf(r4.z, zv1[q * 4 + 2], g0);
        g1 = fmaf(r4.w, zv1[q * 4 + 3], g1);
      }
      float4 kq2 = lds4[kbase + (2 ^ kl7)];   // kept for zqA
      a0 = fmaf(kq2.x, zv0[8], a0);  a1 = fmaf(kq2.y, zv0[9], a1);
      a0 = fmaf(kq2.z, zv0[10], a0); a1 = fmaf(kq2.w, zv0[11], a1);
      g0 = fmaf(kq2.x, zv1[8], g0);  g1 = fmaf(kq2.y, zv1[9], g1);
      g0 = fmaf(kq2.z, zv1[10], g0); g1 = fmaf(kq2.w, zv1[11], g1);
      float4 kq3 = lds4[kbase + (3 ^ kl7)];   // kept for zqA
      a0 = fmaf(kq3.x, zv0[12], a0); a1 = fmaf(kq3.y, zv0[13], a1);
      a0 = fmaf(kq3.z, zv0[14], a0); a1 = fmaf(kq3.w, zv0[15], a1);
      g0 = fmaf(kq3.x, zv1[12], g0); g1 = fmaf(kq3.y, zv1[13], g1);
      g0 = fmaf(kq3.z, zv1[14], g0); g1 = fmaf(kq3.w, zv1[15], g1);

      float s0 = (a0 + a1) - 0.5f * cq;  // logits + const(n)
      float s1 = (g0 + g1) - 0.5f * cq;
      float ev0 = __expf(s0), ev1 = __expf(s1);
      S0 += ev0;  S1 += ev1;
      es0 = fmaf(ev0, s0, es0);
      es1 = fmaf(ev1, s1, es1);
      // zqA: re-read quads 0,1; consume kept kq2,kq3
#pragma unroll
      for (int q = 0; q < 2; ++q) {
        float4 r4 = lds4[kbase + (q ^ kl7)];
        zqA0[q * 4 + 0] = fmaf(ev0, r4.x, zqA0[q * 4 + 0]);
        zqA0[q * 4 + 1] = fmaf(ev0, r4.y, zqA0[q * 4 + 1]);
        zqA0[q * 4 + 2] = fmaf(ev0, r4.z, zqA0[q * 4 + 2]);
        zqA0[q * 4 + 3] = fmaf(ev0, r4.w, zqA0[q * 4 + 3]);
        zqA1[q * 4 + 0] = fmaf(ev1, r4.x, zqA1[q * 4 + 0]);
        zqA1[q * 4 + 1] = fmaf(ev1, r4.y, zqA1[q * 4 + 1]);
        zqA1[q * 4 + 2] = fmaf(ev1, r4.z, zqA1[q * 4 + 2]);
        zqA1[q * 4 + 3] = fmaf(ev1, r4.w, zqA1[q * 4 + 3]);
      }
      zqA0[8]  = fmaf(ev0, kq2.x, zqA0[8]);  zqA0[9]  = fmaf(ev0, kq2.y, zqA0[9]);
      zqA0[10] = fmaf(ev0, kq2.z, zqA0[10]); zqA0[11] = fmaf(ev0, kq2.w, zqA0[11]);
      zqA1[8]  = fmaf(ev1, kq2.x, zqA1[8]);  zqA1[9]  = fmaf(ev1, kq2.y, zqA1[9]);
      zqA1[10] = fmaf(ev1, kq2.z, zqA1[10]); zqA1[11] = fmaf(ev1, kq2.w, zqA1[11]);
      zqA0[12] = fmaf(ev0, kq3.x, zqA0[12]); zqA0[13] = fmaf(ev0, kq3.y, zqA0[13]);
      zqA0[14] = fmaf(ev0, kq3.z, zqA0[14]); zqA0[15] = fmaf(ev0, kq3.w, zqA0[15]);
      zqA1[12] = fmaf(ev1, kq3.x, zqA1[12]); zqA1[13] = fmaf(ev1, kq3.y, zqA1[13]);
      zqA1[14] = fmaf(ev1, kq3.z, zqA1[14]); zqA1[15] = fmaf(ev1, kq3.w, zqA1[15]);
    }

    float St0 = wsum64(S0), St1 = wsum64(S1);
    float rS0 = 1.f / St0, rS1 = 1.f / St1;
    float est0 = wsum64(es0), est1 = wsum64(es1);

    accA1 += (zs0 - 2.f * est0 * rS0) + (zs1 - 2.f * est1 * rS1);
    accA2 += (est0 * rS0 - __logf(St0)) + (est1 * rS1 - __logf(St1));

    // ---- butterfly A now: zqA regs die before sweep 2 ---------------------
    {
#pragma unroll
      for (int t = 0; t < 4; ++t) {
        const int half = 8 >> t;
        const int up = (lane >> (5 - t)) & 1;
#pragma unroll
        for (int i = 0; i < half; ++i) {
          float sa0 = up ? zqA0[i] : zqA0[i + half];
          float ka0 = up ? zqA0[i + half] : zqA0[i];
          zqA0[i] = ka0 + __shfl_xor(sa0, 32 >> t, 64);
          float sa1 = up ? zqA1[i] : zqA1[i + half];
          float ka1 = up ? zqA1[i + half] : zqA1[i];
          zqA1[i] = ka1 + __shfl_xor(sa1, 32 >> t, 64);
        }
      }
      zqA0[0] += __shfl_xor(zqA0[0], 2, 64);
      zqA0[0] += __shfl_xor(zqA0[0], 1, 64);
      zqA1[0] += __shfl_xor(zqA1[0], 2, 64);
      zqA1[0] += __shfl_xor(zqA1[0], 1, 64);
      const int ddA = (lane >> 2) & 15;       // d = ddA, 4 lanes per d
      float dA0 = z_lds[nl0 * ZLD + ddA] - zqA0[0] * rS0;  // normalize here
      float dA1 = z_lds[nl1 * ZLD + ddA] - zqA1[0] * rS1;
      a0loc += dA0 * dA0 + dA1 * dA1;         // deferred reduction (R11b)
    }

    // ---- sweep 2: recompute dot (keep 4..7) -> argmax, qv, store, zqB -----
    float sm0 = -INFINITY, sm1 = -INFINITY;
    int km0 = 0, km1 = 0;
    float zqB0[16], zqB1[16];
#pragma unroll
    for (int i = 0; i < 16; ++i) { zqB0[i] = 0.f; zqB1[i] = 0.f; }
    float* qp0 = out_q + ((size_t)n0 * 8 + c) * 1024;
    float* qp1 = out_q + ((size_t)n1 * 8 + c) * 1024;

#pragma unroll 1
    for (int jj = 0; jj < 16; ++jj) {
      const int k = jj * 64 + lane;
      const int kbase = k << 3;
      float cq = cbsq_lds[k];
      float a0 = 0.f, a1 = 0.f, g0 = 0.f, g1 = 0.f;
#pragma unroll
      for (int q = 0; q < 4; ++q) {      // q = 0..3 (discard)
        float4 r4 = lds4[kbase + (q ^ kl7)];
        a0 = fmaf(r4.x, zv0[q * 4 + 0], a0);
        a1 = fmaf(r4.y, zv0[q * 4 + 1], a1);
        a0 = fmaf(r4.z, zv0[q * 4 + 2], a0);
        a1 = fmaf(r4.w, zv0[q * 4 + 3], a1);
        g0 = fmaf(r4.x, zv1[q * 4 + 0], g0);
        g1 = fmaf(r4.y, zv1[q * 4 + 1], g1);
        g0 = fmaf(r4.z, zv1[q * 4 + 2], g0);
        g1 = fmaf(r4.w, zv1[q * 4 + 3], g1);
      }
      float4 kq4 = lds4[kbase + (4 ^ kl7)];   // kept for zqB
      a0 = fmaf(kq4.x, zv0[16], a0); a1 = fmaf(kq4.y, zv0[17], a1);
      a0 = fmaf(kq4.z, zv0[18], a0); a1 = fmaf(kq4.w, zv0[19], a1);
      g0 = fmaf(kq4.x, zv1[16], g0); g1 = fmaf(kq4.y, zv1[17], g1);
      g0 = fmaf(kq4.z, zv1[18], g0); g1 = fmaf(kq4.w, zv1[19], g1);
      float4 kq5 = lds4[kbase + (5 ^ kl7)];   // kept for zqB
      a0 = fmaf(kq5.x, zv0[20], a0); a1 = fmaf(kq5.y, zv0[21], a1);
      a0 = fmaf(kq5.z, zv0[22], a0); a1 = fmaf(kq5.w, zv0[23], a1);
      g0 = fmaf(kq5.x, zv1[20], g0); g1 = fmaf(kq5.y, zv1[21], g1);
      g0 = fmaf(kq5.z, zv1[22], g0); g1 = fmaf(kq5.w, zv1[23], g1);
      float4 kq6 = lds4[kbase + (6 ^ kl7)];   // kept for zqB
      a0 = fmaf(kq6.x, zv0[24], a0); a1 = fmaf(kq6.y, zv0[25], a1);
      a0 = fmaf(kq6.z, zv0[26], a0); a1 = fmaf(kq6.w, zv0[27], a1);
      g0 = fmaf(kq6.x, zv1[24], g0); g1 = fmaf(kq6.y, zv1[25], g1);
      g0 = fmaf(kq6.z, zv1[26], g0); g1 = fmaf(kq6.w, zv1[27], g1);
      float4 kq7 = lds4[kbase + (7 ^ kl7)];   // kept for zqB
      a0 = fmaf(kq7.x, zv0[28], a0); a1 = fmaf(kq7.y, zv0[29], a1);
      a0 = fmaf(kq7.z, zv0[30], a0); a1 = fmaf(kq7.w, zv0[31], a1);
      g0 = fmaf(kq7.x, zv1[28], g0); g1 = fmaf(kq7.y, zv1[29], g1);
      g0 = fmaf(kq7.z, zv1[30], g0); g1 = fmaf(kq7.w, zv1[31], g1);

      float s0 = (a0 + a1) - 0.5f * cq;
      float s1 = (g0 + g1) - 0.5f * cq;
      if (s0 > sm0) { sm0 = s0; km0 = k; }
      if (s1 > sm1) { sm1 = s1; km1 = k; }
      float qv0 = __expf(s0) * rS0;
      float qv1 = __expf(s1) * rS1;
      __builtin_nontemporal_store(qv0, qp0 + jj * 64 + lane);
      __builtin_nontemporal_store(qv1, qp1 + jj * 64 + lane);
      atomicAdd(&qsum[jj * 64 + lane], qv0 + qv1);
      // zqB from kept kq4..kq7 (d = 16 + (q-4)*4 + e)
      zqB0[0]  = fmaf(qv0, kq4.x, zqB0[0]);  zqB0[1]  = fmaf(qv0, kq4.y, zqB0[1]);
      zqB0[2]  = fmaf(qv0, kq4.z, zqB0[2]);  zqB0[3]  = fmaf(qv0, kq4.w, zqB0[3]);
      zqB1[0]  = fmaf(qv1, kq4.x, zqB1[0]);  zqB1[1]  = fmaf(qv1, kq4.y, zqB1[1]);
      zqB1[2]  = fmaf(qv1, kq4.z, zqB1[2]);  zqB1[3]  = fmaf(qv1, kq4.w, zqB1[3]);
      zqB0[4]  = fmaf(qv0, kq5.x, zqB0[4]);  zqB0[5]  = fmaf(qv0, kq5.y, zqB0[5]);
      zqB0[6]  = fmaf(qv0, kq5.z, zqB0[6]);  zqB0[7]  = fmaf(qv0, kq5.w, zqB0[7]);
      zqB1[4]  = fmaf(qv1, kq5.x, zqB1[4]);  zqB1[5]  = fmaf(qv1, kq5.y, zqB1[5]);
      zqB1[6]  = fmaf(qv1, kq5.z, zqB1[6]);  zqB1[7]  = fmaf(qv1, kq5.w, zqB1[7]);
      zqB0[8]  = fmaf(qv0, kq6.x, zqB0[8]);  zqB0[9]  = fmaf(qv0, kq6.y, zqB0[9]);
      zqB0[10] = fmaf(qv0, kq6.z, zqB0[10]); zqB0[11] = fmaf(qv0, kq6.w, zqB0[11]);
      zqB1[8]  = fmaf(qv1, kq6.x, zqB1[8]);  zqB1[9]  = fmaf(qv1, kq6.y, zqB1[9]);
      zqB1[10] = fmaf(qv1, kq6.z, zqB1[10]); zqB1[11] = fmaf(qv1, kq6.w, zqB1[11]);
      zqB0[12] = fmaf(qv0, kq7.x, zqB0[12]); zqB0[13] = fmaf(qv0, kq7.y, zqB0[13]);
      zqB0[14] = fmaf(qv0, kq7.z, zqB0[14]); zqB0[15] = fmaf(qv0, kq7.w, zqB0[15]);
      zqB1[12] = fmaf(qv1, kq7.x, zqB1[12]); zqB1[13] = fmaf(qv1, kq7.y, zqB1[13]);
      zqB1[14] = fmaf(qv1, kq7.z, zqB1[14]); zqB1[15] = fmaf(qv1, kq7.w, zqB1[15]);
    }

    // ---- argmax(s) == argmin(dist), tie -> lower k ------------------------
#pragma unroll
    for (int m = 32; m >= 1; m >>= 1) {
      float so = __shfl_xor(sm0, m, 64); int ko = __shfl_xor(km0, m, 64);
      if (so > sm0 || (so == sm0 && ko < km0)) { sm0 = so; km0 = ko; }
      float sp = __shfl_xor(sm1, m, 64); int kp = __shfl_xor(km1, m, 64);
      if (sp > sm1 || (sp == sm1 && kp < km1)) { sm1 = sp; km1 = kp; }
    }
    if (lane == 0) {
      out_idx[(size_t)bb * 8192 + c * 1024 + hwb + nl0] = (float)km0;
      ws_i[WS_IDX + n0 * 8 + c] = km0;
      out_idx[(size_t)bb * 8192 + c * 1024 + hwb + nl1] = (float)km1;
      ws_i[WS_IDX + n1 * 8 + c] = km1;
    }

    // ---- butterfly B ------------------------------------------------------
#pragma unroll
    for (int t = 0; t < 4; ++t) {
      const int half = 8 >> t;
      const int up = (lane >> (5 - t)) & 1;
#pragma unroll
      for (int i = 0; i < half; ++i) {
        float sa0 = up ? zqB0[i] : zqB0[i + half];
        float ka0 = up ? zqB0[i + half] : zqB0[i];
        zqB0[i] = ka0 + __shfl_xor(sa0, 32 >> t, 64);
        float sa1 = up ? zqB1[i] : zqB1[i + half];
        float ka1 = up ? zqB1[i + half] : zqB1[i];
        zqB1[i] = ka1 + __shfl_xor(sa1, 32 >> t, 64);
      }
    }
    zqB0[0] += __shfl_xor(zqB0[0], 2, 64);
    zqB0[0] += __shfl_xor(zqB0[0], 1, 64);
    zqB1[0] += __shfl_xor(zqB1[0], 2, 64);
    zqB1[0] += __shfl_xor(zqB1[0], 1, 64);
    const int ddB = (lane >> 2) & 15;       // d = 16 + ddB
    float dB0 = z_lds[nl0 * ZLD + 16 + ddB] - zqB0[0];  // qv already norm'd
    float dB1 = z_lds[nl1 * ZLD + 16 + ddB] - zqB1[0];
    a0loc += dB0 * dB0 + dB1 * dB1;         // deferred reduction (R11b)
  }

  // deferred commitment reduction: each d counted 4x across lanes -> 0.25
  float accA0 = 0.25f * wsum64(a0loc);
  if (lane == 0) {
    atomicAdd(&ws_f[WS_A0], accA0);
    atomicAdd(&ws_f[WS_A1], accA1);
    atomicAdd(&ws_f[WS_A2], accA2);
  }

  // ---- q_bar: block LDS accumulator -> global -----------------------------
  __syncthreads();
  atomicAdd(&ws_f[WS_QBAR + c * 1024 + tid], qsum[tid]);
}

// hard-quantized gather (float4: 4 hw per thread) + scalar finalization
// (block 0). k_main->k_hard kernel boundary orders all ws_f/ws_i writes.
__global__ __launch_bounds__(256) void k_hard(const float* __restrict__ cb,
                                              const int* __restrict__ ws_i,
                                              float* __restrict__ out0,
                                              const float* __restrict__ ws_f,
                                              float* __restrict__ out_s) {
  int o4 = blockIdx.x * 256 + threadIdx.x;   // float4 index 0..262143
  int o  = o4 << 2;                          // (b, ch, hw) row-major
  int b  = o >> 18;
  int r  = o & 262143;
  int ch = r >> 10;
  int hw = r & 1023;                         // hw..hw+3, same ch
  int c = ch >> 5, dd = ch & 31;
  int n = (b << 10) + hw;
  const int* ip = ws_i + WS_IDX + n * 8 + c;
  const float* cbc = cb + ((size_t)c << 15) + dd;
  float4 v;
  v.x = cbc[(size_t)ip[0]  * 32];
  v.y = cbc[(size_t)ip[8]  * 32];
  v.z = cbc[(size_t)ip[16] * 32];
  v.w = cbc[(size_t)ip[24] * 32];
  *(float4*)(out0 + o) = v;

  if (blockIdx.x == 0) {                     // block-uniform branch
    __shared__ float red[256];
    int tid = threadIdx.x;
    float bal = 0.f;
    for (int i = tid; i < 8192; i += 256) {
      float qb = ws_f[WS_QBAR + i] * (1.0f / 4096.0f);
      bal += qb * __logf(qb * 1024.0f + 1e-8f);
    }
    red[tid] = bal;
    __syncthreads();
    for (int s = 128; s > 0; s >>= 1) {
      if (tid < s) red[tid] += red[tid + s];
      __syncthreads();
    }
    if (tid == 0) {
      float A0 = ws_f[WS_A0], A1 = ws_f[WS_A1], A2 = ws_f[WS_A2];
      out_s[0] = A0 * (1.0f / 1048576.0f);                              // commitment
      out_s[1] = (0.5f * A1 + A2) * (1.0f / 32768.0f) + 6.93147180559945f; // free_energy
      out_s[2] = -A2 * (1.0f / 32768.0f);                               // confidence
      out_s[3] = red[0] * 0.125f;                                       // balance
      out_s[4] = 1.0f;                                                  // tau
    }
  }
}

extern "C" void kernel_launch(void* const* d_in, const int* in_sizes, int n_in,
                              void* d_out, int out_size, void* d_ws, size_t ws_size,
                              hipStream_t stream) {
  (void)in_sizes; (void)n_in; (void)out_size; (void)ws_size;
  const float* z  = (const float*)d_in[0];
  const float* cb = (const float*)d_in[1];
  float* out  = (float*)d_out;
  float* ws_f = (float*)d_ws;
  int*   ws_i = (int*)d_ws;

  hipMemsetAsync(d_ws, 0, (WS_QBAR + 8192) * sizeof(float), stream);
  k_main <<<256, 1024, 0, stream>>>(z, cb, out, ws_f, ws_i);
  k_hard <<<1024, 256, 0, stream>>>(cb, ws_i, out, ws_f, out + OUT_SCAL);
}

// Round 10
// 408.308 us; speedup vs baseline: 1.3625x; 1.0687x over previous
//
#include <hip/hip_runtime.h>

// ---------------- workspace layout (float indices into d_ws) --------------
#define WS_A0 0              // commitment sum
#define WS_A1 1              // sum of E_dist over (n,c)
#define WS_A2 2              // sum of neg_ent over (n,c)
#define WS_QBAR 16           // 8192 floats: sum_n q[n,c,k]

// ---------------- output layout (floats) ----------------------------------
#define OUT_IDX  1048576     // indices (B,C,H,W) as float
#define OUT_Q    1081344     // q (N,C,K)
#define OUT_SCAL 34635776    // commitment, free_energy, confidence, balance, tau

__device__ __forceinline__ float wsum64(float v) {
#pragma unroll
  for (int m = 32; m >= 1; m >>= 1) v += __shfl_xor(v, m, 64);
  return v;
}

__device__ __forceinline__ float uread(float v) {
  // wave-uniform value -> SGPR (exact; all lanes hold the same bits)
  return __int_as_float(__builtin_amdgcn_readfirstlane(__float_as_int(v)));
}

// main: 256 blocks (8 c x 32 n-blocks), 1024 threads (16 waves), ~153KB LDS.
// R9: 64-VGPR-native two-sweep structure. R10: keep-2 forwarding, fused
// cbsq. R11: sweep-2 keep-4, deferred commitment reduction, f4 k_hard.
// R12: (a) sweep-1 keep-4 too -- zqA entirely from kept kq0..kq3:
// 18 -> 16 b128/jj/pair (measured lever: ~12us wall per read/jj removed).
// (b) hard-quantize gather FUSED into k_main's epilogue: all lanes hold km
// after the argmax butterfly; stage km_lds[128], then write the block's
// 4096 out0 floats from the LDS codebook with coalesced 256B runs.
// k_hard deleted (ws_i dead); tail is a tiny 1-block k_final.
// (c) es-reduction deferred per-lane (Σ est*rS is linear): 2 of 4 wsum64
// per pair removed from the serial inter-sweep path.
#define ZLD 33               // z_lds leading dim (+1 pad: write stride 33)
__global__ __launch_bounds__(1024, 4)
void k_main(
    const float* __restrict__ z, const float* __restrict__ cb,
    float* __restrict__ out, float* __restrict__ ws_f) {
  // 39040 floats = 156160 B + 512 B km  (<= 163840 on gfx950)
  __shared__ __attribute__((aligned(16))) float smem[39040];
  __shared__ int km_lds[128];
  float* cb_lds   = smem;              // 32768 floats, xor-swizzled quads
  float* qsum     = smem + 32768;      // 1024 floats: per-block sum_n q
  float* cbsq_lds = smem + 33792;      // 1024 floats: ||cb[c,k]||^2
  float* z_lds    = smem + 34816;      // 128*33 floats: z[nl, d] (padded)

  const int c    = blockIdx.x >> 5;
  const int nblk = blockIdx.x & 31;
  const int tid  = threadIdx.x;
  const int lane = tid & 63;
  const int wave = tid >> 6;           // 0..15

  const int bb   = (nblk * 128) >> 10;      // batch index, constant per block
  const int hwb  = (nblk * 128) & 1023;     // hw base, constant per block

  // ---- stage full channel codebook into LDS, quad-xor swizzle -------------
  const float4* cb4 = (const float4*)(cb + (size_t)c * 32768);
  float4* lds4 = (float4*)cb_lds;
#pragma unroll
  for (int i = 0; i < 8; ++i) {
    int idx = i * 1024 + tid;           // float4 index 0..8191
    int k = idx >> 3, q = idx & 7;
    lds4[(k << 3) + (q ^ (k & 7))] = cb4[idx];
  }
  qsum[tid] = 0.f;
  // z slice: 128 n x 32 d, coalesced global reads, padded LDS writes
  {
    const float* zbase = z + (((size_t)bb * 256 + c * 32) << 10) + hwb;
#pragma unroll
    for (int i = 0; i < 4; ++i) {
      int idx = i * 1024 + tid;         // 0..4095
      int d = idx >> 7, j = idx & 127;
      z_lds[j * ZLD + d] = zbase[(size_t)d * 1024 + j];
    }
  }
  __syncthreads();
  // cbsq from staged rows: slots q^(tid&7) ascending == quads d-ascending
  {
    float s = 0.f;
    const int t7 = tid & 7;
#pragma unroll
    for (int q = 0; q < 8; ++q) {
      float4 r4 = lds4[(tid << 3) + (q ^ t7)];
      s = fmaf(r4.x, r4.x, s); s = fmaf(r4.y, r4.y, s);
      s = fmaf(r4.z, r4.z, s); s = fmaf(r4.w, r4.w, s);
    }
    cbsq_lds[tid] = s;
  }
  __syncthreads();

  float* out_q   = out + OUT_Q;
  float* out_idx = out + OUT_IDX;

  float zsum = 0.f;                     // uniform: sum of zs
  float logsum = 0.f;                   // uniform: sum of log(St)
  float a12loc = 0.f;                   // per-lane: sum of es*rS (R12c)
  float a0loc = 0.f;                    // per-lane commitment partial
  const int kl7 = lane & 7;

#pragma unroll 1
  for (int pp = 0; pp < 4; ++pp) {      // each wave: 4 pairs of n
    const int nl0 = wave * 8 + pp * 2;  // local n in [0,128)
    const int nl1 = nl0 + 1;
    const int n0 = nblk * 128 + nl0;
    const int n1 = n0 + 1;

    // wave-uniform z (LDS broadcast) -> SGPRs
    float zv0[32], zv1[32];
#pragma unroll
    for (int d = 0; d < 32; ++d) {
      zv0[d] = uread(z_lds[nl0 * ZLD + d]);
      zv1[d] = uread(z_lds[nl1 * ZLD + d]);
    }
    float zs0 = 0.f, zs1 = 0.f;
#pragma unroll
    for (int d = 0; d < 32; ++d) {
      zs0 = fmaf(zv0[d], zv0[d], zs0);
      zs1 = fmaf(zv1[d], zv1[d], zs1);
    }
    zsum += zs0 + zs1;

    // ---- sweep 1: dot (keep quads 0..3) + S/es + zqA (d 0..15) ------------
    float S0 = 0.f, S1 = 0.f, es0 = 0.f, es1 = 0.f;
    float zqA0[16], zqA1[16];
#pragma unroll
    for (int i = 0; i < 16; ++i) { zqA0[i] = 0.f; zqA1[i] = 0.f; }

#pragma unroll 1
    for (int jj = 0; jj < 16; ++jj) {   // k = jj*64 + lane, covers K=1024
      const int k = jj * 64 + lane;
      const int kbase = k << 3;
      float cq = cbsq_lds[k];
      float a0 = 0.f, a1 = 0.f, g0 = 0.f, g1 = 0.f;
#pragma unroll
      for (int q = 4; q < 8; ++q) {      // q = 4..7 (discard)
        float4 r4 = lds4[kbase + (q ^ kl7)];
        a0 = fmaf(r4.x, zv0[q * 4 + 0], a0);
        a1 = fmaf(r4.y, zv0[q * 4 + 1], a1);
        a0 = fmaf(r4.z, zv0[q * 4 + 2], a0);
        a1 = fmaf(r4.w, zv0[q * 4 + 3], a1);
        g0 = fmaf(r4.x, zv1[q * 4 + 0], g0);
        g1 = fmaf(r4.y, zv1[q * 4 + 1], g1);
        g0 = fmaf(r4.z, zv1[q * 4 + 2], g0);
        g1 = fmaf(r4.w, zv1[q * 4 + 3], g1);
      }
      float4 kq0 = lds4[kbase + (0 ^ kl7)];   // kept for zqA
      a0 = fmaf(kq0.x, zv0[0], a0);  a1 = fmaf(kq0.y, zv0[1], a1);
      a0 = fmaf(kq0.z, zv0[2], a0);  a1 = fmaf(kq0.w, zv0[3], a1);
      g0 = fmaf(kq0.x, zv1[0], g0);  g1 = fmaf(kq0.y, zv1[1], g1);
      g0 = fmaf(kq0.z, zv1[2], g0);  g1 = fmaf(kq0.w, zv1[3], g1);
      float4 kq1 = lds4[kbase + (1 ^ kl7)];   // kept for zqA
      a0 = fmaf(kq1.x, zv0[4], a0);  a1 = fmaf(kq1.y, zv0[5], a1);
      a0 = fmaf(kq1.z, zv0[6], a0);  a1 = fmaf(kq1.w, zv0[7], a1);
      g0 = fmaf(kq1.x, zv1[4], g0);  g1 = fmaf(kq1.y, zv1[5], g1);
      g0 = fmaf(kq1.z, zv1[6], g0);  g1 = fmaf(kq1.w, zv1[7], g1);
      float4 kq2 = lds4[kbase + (2 ^ kl7)];   // kept for zqA
      a0 = fmaf(kq2.x, zv0[8], a0);  a1 = fmaf(kq2.y, zv0[9], a1);
      a0 = fmaf(kq2.z, zv0[10], a0); a1 = fmaf(kq2.w, zv0[11], a1);
      g0 = fmaf(kq2.x, zv1[8], g0);  g1 = fmaf(kq2.y, zv1[9], g1);
      g0 = fmaf(kq2.z, zv1[10], g0); g1 = fmaf(kq2.w, zv1[11], g1);
      float4 kq3 = lds4[kbase + (3 ^ kl7)];   // kept for zqA
      a0 = fmaf(kq3.x, zv0[12], a0); a1 = fmaf(kq3.y, zv0[13], a1);
      a0 = fmaf(kq3.z, zv0[14], a0); a1 = fmaf(kq3.w, zv0[15], a1);
      g0 = fmaf(kq3.x, zv1[12], g0); g1 = fmaf(kq3.y, zv1[13], g1);
      g0 = fmaf(kq3.z, zv1[14], g0); g1 = fmaf(kq3.w, zv1[15], g1);

      float s0 = (a0 + a1) - 0.5f * cq;  // logits + const(n)
      float s1 = (g0 + g1) - 0.5f * cq;
      float ev0 = __expf(s0), ev1 = __expf(s1);
      S0 += ev0;  S1 += ev1;
      es0 = fmaf(ev0, s0, es0);
      es1 = fmaf(ev1, s1, es1);
      // zqA entirely from kept kq0..kq3 (d = q*4 + e)
      zqA0[0]  = fmaf(ev0, kq0.x, zqA0[0]);  zqA0[1]  = fmaf(ev0, kq0.y, zqA0[1]);
      zqA0[2]  = fmaf(ev0, kq0.z, zqA0[2]);  zqA0[3]  = fmaf(ev0, kq0.w, zqA0[3]);
      zqA1[0]  = fmaf(ev1, kq0.x, zqA1[0]);  zqA1[1]  = fmaf(ev1, kq0.y, zqA1[1]);
      zqA1[2]  = fmaf(ev1, kq0.z, zqA1[2]);  zqA1[3]  = fmaf(ev1, kq0.w, zqA1[3]);
      zqA0[4]  = fmaf(ev0, kq1.x, zqA0[4]);  zqA0[5]  = fmaf(ev0, kq1.y, zqA0[5]);
      zqA0[6]  = fmaf(ev0, kq1.z, zqA0[6]);  zqA0[7]  = fmaf(ev0, kq1.w, zqA0[7]);
      zqA1[4]  = fmaf(ev1, kq1.x, zqA1[4]);  zqA1[5]  = fmaf(ev1, kq1.y, zqA1[5]);
      zqA1[6]  = fmaf(ev1, kq1.z, zqA1[6]);  zqA1[7]  = fmaf(ev1, kq1.w, zqA1[7]);
      zqA0[8]  = fmaf(ev0, kq2.x, zqA0[8]);  zqA0[9]  = fmaf(ev0, kq2.y, zqA0[9]);
      zqA0[10] = fmaf(ev0, kq2.z, zqA0[10]); zqA0[11] = fmaf(ev0, kq2.w, zqA0[11]);
      zqA1[8]  = fmaf(ev1, kq2.x, zqA1[8]);  zqA1[9]  = fmaf(ev1, kq2.y, zqA1[9]);
      zqA1[10] = fmaf(ev1, kq2.z, zqA1[10]); zqA1[11] = fmaf(ev1, kq2.w, zqA1[11]);
      zqA0[12] = fmaf(ev0, kq3.x, zqA0[12]); zqA0[13] = fmaf(ev0, kq3.y, zqA0[13]);
      zqA0[14] = fmaf(ev0, kq3.z, zqA0[14]); zqA0[15] = fmaf(ev0, kq3.w, zqA0[15]);
      zqA1[12] = fmaf(ev1, kq3.x, zqA1[12]); zqA1[13] = fmaf(ev1, kq3.y, zqA1[13]);
      zqA1[14] = fmaf(ev1, kq3.z, zqA1[14]); zqA1[15] = fmaf(ev1, kq3.w, zqA1[15]);
    }

    float St0 = wsum64(S0), St1 = wsum64(S1);
    float rS0 = 1.f / St0, rS1 = 1.f / St1;
    a12loc += es0 * rS0 + es1 * rS1;    // deferred (R12c)
    logsum += __logf(St0) + __logf(St1);

    // ---- butterfly A now: zqA regs die before sweep 2 ---------------------
    {
#pragma unroll
      for (int t = 0; t < 4; ++t) {
        const int half = 8 >> t;
        const int up = (lane >> (5 - t)) & 1;
#pragma unroll
        for (int i = 0; i < half; ++i) {
          float sa0 = up ? zqA0[i] : zqA0[i + half];
          float ka0 = up ? zqA0[i + half] : zqA0[i];
          zqA0[i] = ka0 + __shfl_xor(sa0, 32 >> t, 64);
          float sa1 = up ? zqA1[i] : zqA1[i + half];
          float ka1 = up ? zqA1[i + half] : zqA1[i];
          zqA1[i] = ka1 + __shfl_xor(sa1, 32 >> t, 64);
        }
      }
      zqA0[0] += __shfl_xor(zqA0[0], 2, 64);
      zqA0[0] += __shfl_xor(zqA0[0], 1, 64);
      zqA1[0] += __shfl_xor(zqA1[0], 2, 64);
      zqA1[0] += __shfl_xor(zqA1[0], 1, 64);
      const int ddA = (lane >> 2) & 15;       // d = ddA, 4 lanes per d
      float dA0 = z_lds[nl0 * ZLD + ddA] - zqA0[0] * rS0;  // normalize here
      float dA1 = z_lds[nl1 * ZLD + ddA] - zqA1[0] * rS1;
      a0loc += dA0 * dA0 + dA1 * dA1;
    }

    // ---- sweep 2: recompute dot (keep 4..7) -> argmax, qv, store, zqB -----
    float sm0 = -INFINITY, sm1 = -INFINITY;
    int km0 = 0, km1 = 0;
    float zqB0[16], zqB1[16];
#pragma unroll
    for (int i = 0; i < 16; ++i) { zqB0[i] = 0.f; zqB1[i] = 0.f; }
    float* qp0 = out_q + ((size_t)n0 * 8 + c) * 1024;
    float* qp1 = out_q + ((size_t)n1 * 8 + c) * 1024;

#pragma unroll 1
    for (int jj = 0; jj < 16; ++jj) {
      const int k = jj * 64 + lane;
      const int kbase = k << 3;
      float cq = cbsq_lds[k];
      float a0 = 0.f, a1 = 0.f, g0 = 0.f, g1 = 0.f;
#pragma unroll
      for (int q = 0; q < 4; ++q) {      // q = 0..3 (discard)
        float4 r4 = lds4[kbase + (q ^ kl7)];
        a0 = fmaf(r4.x, zv0[q * 4 + 0], a0);
        a1 = fmaf(r4.y, zv0[q * 4 + 1], a1);
        a0 = fmaf(r4.z, zv0[q * 4 + 2], a0);
        a1 = fmaf(r4.w, zv0[q * 4 + 3], a1);
        g0 = fmaf(r4.x, zv1[q * 4 + 0], g0);
        g1 = fmaf(r4.y, zv1[q * 4 + 1], g1);
        g0 = fmaf(r4.z, zv1[q * 4 + 2], g0);
        g1 = fmaf(r4.w, zv1[q * 4 + 3], g1);
      }
      float4 kq4 = lds4[kbase + (4 ^ kl7)];   // kept for zqB
      a0 = fmaf(kq4.x, zv0[16], a0); a1 = fmaf(kq4.y, zv0[17], a1);
      a0 = fmaf(kq4.z, zv0[18], a0); a1 = fmaf(kq4.w, zv0[19], a1);
      g0 = fmaf(kq4.x, zv1[16], g0); g1 = fmaf(kq4.y, zv1[17], g1);
      g0 = fmaf(kq4.z, zv1[18], g0); g1 = fmaf(kq4.w, zv1[19], g1);
      float4 kq5 = lds4[kbase + (5 ^ kl7)];   // kept for zqB
      a0 = fmaf(kq5.x, zv0[20], a0); a1 = fmaf(kq5.y, zv0[21], a1);
      a0 = fmaf(kq5.z, zv0[22], a0); a1 = fmaf(kq5.w, zv0[23], a1);
      g0 = fmaf(kq5.x, zv1[20], g0); g1 = fmaf(kq5.y, zv1[21], g1);
      g0 = fmaf(kq5.z, zv1[22], g0); g1 = fmaf(kq5.w, zv1[23], g1);
      float4 kq6 = lds4[kbase + (6 ^ kl7)];   // kept for zqB
      a0 = fmaf(kq6.x, zv0[24], a0); a1 = fmaf(kq6.y, zv0[25], a1);
      a0 = fmaf(kq6.z, zv0[26], a0); a1 = fmaf(kq6.w, zv0[27], a1);
      g0 = fmaf(kq6.x, zv1[24], g0); g1 = fmaf(kq6.y, zv1[25], g1);
      g0 = fmaf(kq6.z, zv1[26], g0); g1 = fmaf(kq6.w, zv1[27], g1);
      float4 kq7 = lds4[kbase + (7 ^ kl7)];   // kept for zqB
      a0 = fmaf(kq7.x, zv0[28], a0); a1 = fmaf(kq7.y, zv0[29], a1);
      a0 = fmaf(kq7.z, zv0[30], a0); a1 = fmaf(kq7.w, zv0[31], a1);
      g0 = fmaf(kq7.x, zv1[28], g0); g1 = fmaf(kq7.y, zv1[29], g1);
      g0 = fmaf(kq7.z, zv1[30], g0); g1 = fmaf(kq7.w, zv1[31], g1);

      float s0 = (a0 + a1) - 0.5f * cq;
      float s1 = (g0 + g1) - 0.5f * cq;
      if (s0 > sm0) { sm0 = s0; km0 = k; }
      if (s1 > sm1) { sm1 = s1; km1 = k; }
      float qv0 = __expf(s0) * rS0;
      float qv1 = __expf(s1) * rS1;
      __builtin_nontemporal_store(qv0, qp0 + jj * 64 + lane);
      __builtin_nontemporal_store(qv1, qp1 + jj * 64 + lane);
      atomicAdd(&qsum[jj * 64 + lane], qv0 + qv1);
      // zqB from kept kq4..kq7 (d = 16 + (q-4)*4 + e)
      zqB0[0]  = fmaf(qv0, kq4.x, zqB0[0]);  zqB0[1]  = fmaf(qv0, kq4.y, zqB0[1]);
      zqB0[2]  = fmaf(qv0, kq4.z, zqB0[2]);  zqB0[3]  = fmaf(qv0, kq4.w, zqB0[3]);
      zqB1[0]  = fmaf(qv1, kq4.x, zqB1[0]);  zqB1[1]  = fmaf(qv1, kq4.y, zqB1[1]);
      zqB1[2]  = fmaf(qv1, kq4.z, zqB1[2]);  zqB1[3]  = fmaf(qv1, kq4.w, zqB1[3]);
      zqB0[4]  = fmaf(qv0, kq5.x, zqB0[4]);  zqB0[5]  = fmaf(qv0, kq5.y, zqB0[5]);
      zqB0[6]  = fmaf(qv0, kq5.z, zqB0[6]);  zqB0[7]  = fmaf(qv0, kq5.w, zqB0[7]);
      zqB1[4]  = fmaf(qv1, kq5.x, zqB1[4]);  zqB1[5]  = fmaf(qv1, kq5.y, zqB1[5]);
      zqB1[6]  = fmaf(qv1, kq5.z, zqB1[6]);  zqB1[7]  = fmaf(qv1, kq5.w, zqB1[7]);
      zqB0[8]  = fmaf(qv0, kq6.x, zqB0[8]);  zqB0[9]  = fmaf(qv0, kq6.y, zqB0[9]);
      zqB0[10] = fmaf(qv0, kq6.z, zqB0[10]); zqB0[11] = fmaf(qv0, kq6.w, zqB0[11]);
      zqB1[8]  = fmaf(qv1, kq6.x, zqB1[8]);  zqB1[9]  = fmaf(qv1, kq6.y, zqB1[9]);
      zqB1[10] = fmaf(qv1, kq6.z, zqB1[10]); zqB1[11] = fmaf(qv1, kq6.w, zqB1[11]);
      zqB0[12] = fmaf(qv0, kq7.x, zqB0[12]); zqB0[13] = fmaf(qv0, kq7.y, zqB0[13]);
      zqB0[14] = fmaf(qv0, kq7.z, zqB0[14]); zqB0[15] = fmaf(qv0, kq7.w, zqB0[15]);
      zqB1[12] = fmaf(qv1, kq7.x, zqB1[12]); zqB1[13] = fmaf(qv1, kq7.y, zqB1[13]);
      zqB1[14] = fmaf(qv1, kq7.z, zqB1[14]); zqB1[15] = fmaf(qv1, kq7.w, zqB1[15]);
    }

    // ---- argmax(s) == argmin(dist), tie -> lower k ------------------------
#pragma unroll
    for (int m = 32; m >= 1; m >>= 1) {
      float so = __shfl_xor(sm0, m, 64); int ko = __shfl_xor(km0, m, 64);
      if (so > sm0 || (so == sm0 && ko < km0)) { sm0 = so; km0 = ko; }
      float sp = __shfl_xor(sm1, m, 64); int kp = __shfl_xor(km1, m, 64);
      if (sp > sm1 || (sp == sm1 && kp < km1)) { sm1 = sp; km1 = kp; }
    }
    if (lane == 0) {
      out_idx[(size_t)bb * 8192 + c * 1024 + hwb + nl0] = (float)km0;
      out_idx[(size_t)bb * 8192 + c * 1024 + hwb + nl1] = (float)km1;
      km_lds[nl0] = km0;
      km_lds[nl1] = km1;
    }

    // ---- butterfly B ------------------------------------------------------
#pragma unroll
    for (int t = 0; t < 4; ++t) {
      const int half = 8 >> t;
      const int up = (lane >> (5 - t)) & 1;
#pragma unroll
      for (int i = 0; i < half; ++i) {
        float sa0 = up ? zqB0[i] : zqB0[i + half];
        float ka0 = up ? zqB0[i + half] : zqB0[i];
        zqB0[i] = ka0 + __shfl_xor(sa0, 32 >> t, 64);
        float sa1 = up ? zqB1[i] : zqB1[i + half];
        float ka1 = up ? zqB1[i + half] : zqB1[i];
        zqB1[i] = ka1 + __shfl_xor(sa1, 32 >> t, 64);
      }
    }
    zqB0[0] += __shfl_xor(zqB0[0], 2, 64);
    zqB0[0] += __shfl_xor(zqB0[0], 1, 64);
    zqB1[0] += __shfl_xor(zqB1[0], 2, 64);
    zqB1[0] += __shfl_xor(zqB1[0], 1, 64);
    const int ddB = (lane >> 2) & 15;       // d = 16 + ddB
    float dB0 = z_lds[nl0 * ZLD + 16 + ddB] - zqB0[0];  // qv already norm'd
    float dB1 = z_lds[nl1 * ZLD + 16 + ddB] - zqB1[0];
    a0loc += dB0 * dB0 + dB1 * dB1;
  }

  // deferred reductions: each d counted 4x across lanes -> 0.25
  float accA0 = 0.25f * wsum64(a0loc);
  float E = wsum64(a12loc);             // sum of est*rS over this wave's pairs
  if (lane == 0) {
    atomicAdd(&ws_f[WS_A0], accA0);
    atomicAdd(&ws_f[WS_A1], zsum - 2.f * E);
    atomicAdd(&ws_f[WS_A2], E - logsum);
  }

  __syncthreads();
  // ---- q_bar: block LDS accumulator -> global -----------------------------
  atomicAdd(&ws_f[WS_QBAR + c * 1024 + tid], qsum[tid]);

  // ---- fused hard-quantize: coalesced out0 writes from LDS codebook -------
  // out0[(bb*256 + c*32 + dd)*1024 + hwb + nl] = cb[c, km[nl], dd]
#pragma unroll
  for (int i = 0; i < 4; ++i) {
    int idx = i * 1024 + tid;           // 0..4095
    int dd = idx >> 7, nl = idx & 127;
    int km = km_lds[nl];
    int slot = (dd >> 2) ^ (km & 7);
    float v = cb_lds[((km << 3) + slot) * 4 + (dd & 3)];
    out[(((size_t)bb * 256 + c * 32 + dd) << 10) + hwb + nl] = v;
  }
}

// tiny finalization: balance from q_bar + scalar losses (1 block)
__global__ __launch_bounds__(256) void k_final(const float* __restrict__ ws_f,
                                               float* __restrict__ out_s) {
  __shared__ float red[256];
  int tid = threadIdx.x;
  float bal = 0.f;
  for (int i = tid; i < 8192; i += 256) {
    float qb = ws_f[WS_QBAR + i] * (1.0f / 4096.0f);
    bal += qb * __logf(qb * 1024.0f + 1e-8f);
  }
  red[tid] = bal;
  __syncthreads();
  for (int s = 128; s > 0; s >>= 1) {
    if (tid < s) red[tid] += red[tid + s];
    __syncthreads();
  }
  if (tid == 0) {
    float A0 = ws_f[WS_A0], A1 = ws_f[WS_A1], A2 = ws_f[WS_A2];
    out_s[0] = A0 * (1.0f / 1048576.0f);                              // commitment
    out_s[1] = (0.5f * A1 + A2) * (1.0f / 32768.0f) + 6.93147180559945f; // free_energy
    out_s[2] = -A2 * (1.0f / 32768.0f);                               // confidence
    out_s[3] = red[0] * 0.125f;                                       // balance
    out_s[4] = 1.0f;                                                  // tau
  }
}

extern "C" void kernel_launch(void* const* d_in, const int* in_sizes, int n_in,
                              void* d_out, int out_size, void* d_ws, size_t ws_size,
                              hipStream_t stream) {
  (void)in_sizes; (void)n_in; (void)out_size; (void)ws_size;
  const float* z  = (const float*)d_in[0];
  const float* cb = (const float*)d_in[1];
  float* out  = (float*)d_out;
  float* ws_f = (float*)d_ws;

  hipMemsetAsync(d_ws, 0, (WS_QBAR + 8192) * sizeof(float), stream);
  k_main <<<256, 1024, 0, stream>>>(z, cb, out, ws_f);
  k_final<<<1,    256, 0, stream>>>(ws_f, out + OUT_SCAL);
}